// Round 4
// baseline (1193.623 us; speedup 1.0000x reference)
//
#include <hip/hip_runtime.h>

#define N0 262144
#define N1 65536
#define N2 16384
#define NNET 200000
#define E0 2097152
#define E1 524288
#define E2 131072
#define ECONN 800000

// ===== consolidated CSR build =====
// cnt sub-offsets (ints): sizes nSeg+1 each
#define C0 0
#define C1 262145
#define C2 327682
#define C3 344067
#define C4 409604
#define C5 425989
#define CNT_TOT 625990
// cursor sub-offsets (ints): sizes nSeg each
#define U0 0
#define U1 262144
#define U2 327680
#define U3 344064
#define U4 409600
#define U5 425984
// hist/scatter block ranges (256 thr/blk)
#define HB1 8192
#define HB2 10240
#define HB3 10752
#define HB4 11776
#define HB5 12032
#define HTOT 15157
// scan block ranges (2048 elems/blk)
#define SB1 129
#define SB2 162
#define SB3 171
#define SB4 204
#define SB5 213
#define STOT 311

__global__ void hist_all(const int* __restrict__ e0d, const int* __restrict__ e1d,
                         const int* __restrict__ e2d, const int* __restrict__ a01,
                         const int* __restrict__ a12, const int* __restrict__ cd,
                         int* __restrict__ cnt) {
    int bb = blockIdx.x; const int* idx; int nE, lb; int* c;
    if (bb < HB1)      { idx = e0d; nE = E0;    c = cnt + C0; lb = bb; }
    else if (bb < HB2) { idx = e1d; nE = E1;    c = cnt + C1; lb = bb - HB1; }
    else if (bb < HB3) { idx = e2d; nE = E2;    c = cnt + C2; lb = bb - HB2; }
    else if (bb < HB4) { idx = a01; nE = N0;    c = cnt + C3; lb = bb - HB3; }
    else if (bb < HB5) { idx = a12; nE = N1;    c = cnt + C4; lb = bb - HB4; }
    else               { idx = cd;  nE = ECONN; c = cnt + C5; lb = bb - HB5; }
    int t = lb * 256 + threadIdx.x;
    if (t < nE) atomicAdd(&c[idx[t]], 1);
}

__global__ void scan1_all(const int* __restrict__ cnt, int* rp0, int* rp1, int* rp2,
                          int* rpA01, int* rpA12, int* rpC, int* __restrict__ partials) {
    int bb = blockIdx.x; const int* in; int* out; int n, lb;
    if (bb < SB1)      { in = cnt + C0; out = rp0;   n = N0 + 1;   lb = bb; }
    else if (bb < SB2) { in = cnt + C1; out = rp1;   n = N1 + 1;   lb = bb - SB1; }
    else if (bb < SB3) { in = cnt + C2; out = rp2;   n = N2 + 1;   lb = bb - SB2; }
    else if (bb < SB4) { in = cnt + C3; out = rpA01; n = N1 + 1;   lb = bb - SB3; }
    else if (bb < SB5) { in = cnt + C4; out = rpA12; n = N2 + 1;   lb = bb - SB4; }
    else               { in = cnt + C5; out = rpC;   n = NNET + 1; lb = bb - SB5; }
    __shared__ int ts[256];
    int t = threadIdx.x;
    int base = lb * 2048 + t * 8;
    int v[8]; int s = 0;
#pragma unroll
    for (int k = 0; k < 8; ++k) { int i = base + k; v[k] = (i < n) ? in[i] : 0; s += v[k]; }
    ts[t] = s; __syncthreads();
    for (int off = 1; off < 256; off <<= 1) {
        int u = (t >= off) ? ts[t - off] : 0; __syncthreads();
        ts[t] += u; __syncthreads();
    }
    if (t == 255) partials[bb] = ts[255];
    int run = ts[t] - s;
#pragma unroll
    for (int k = 0; k < 8; ++k) { int i = base + k; if (i < n) out[i] = run; run += v[k]; }
}

__global__ void scan2_all(int* __restrict__ partials) {
    const int PO[6] = {0, SB1, SB2, SB3, SB4, SB5};
    const int NP[6] = {SB1, SB2 - SB1, SB3 - SB2, SB4 - SB3, SB5 - SB4, STOT - SB5};
    int b = blockIdx.x;
    int* p = partials + PO[b]; int np = NP[b];
    __shared__ int ts[256];
    int t = threadIdx.x;
    int v = (t < np) ? p[t] : 0;
    ts[t] = v; __syncthreads();
    for (int off = 1; off < 256; off <<= 1) {
        int u = (t >= off) ? ts[t - off] : 0; __syncthreads();
        ts[t] += u; __syncthreads();
    }
    if (t < np) p[t] = ts[t] - v;
}

__global__ void scan3_all(int* rp0, int* rp1, int* rp2, int* rpA01, int* rpA12, int* rpC,
                          const int* __restrict__ partials, int* __restrict__ cur) {
    int bb = blockIdx.x; int* out; int n, lb; int* cu;
    if (bb < SB1)      { out = rp0;   n = N0 + 1;   lb = bb;       cu = cur + U0; }
    else if (bb < SB2) { out = rp1;   n = N1 + 1;   lb = bb - SB1; cu = cur + U1; }
    else if (bb < SB3) { out = rp2;   n = N2 + 1;   lb = bb - SB2; cu = cur + U2; }
    else if (bb < SB4) { out = rpA01; n = N1 + 1;   lb = bb - SB3; cu = cur + U3; }
    else if (bb < SB5) { out = rpA12; n = N2 + 1;   lb = bb - SB4; cu = cur + U4; }
    else               { out = rpC;   n = NNET + 1; lb = bb - SB5; cu = cur + U5; }
    int add = partials[bb];
    int base = lb * 2048;
#pragma unroll
    for (int k = 0; k < 8; ++k) {
        int i = base + k * 256 + threadIdx.x;
        if (i < n) {
            int v = out[i] + add;
            out[i] = v;
            if (i < n - 1) cu[i] = v;
        }
    }
}

__global__ void scatter_all(const int* e0s, const int* e0d, const int* e1s, const int* e1d,
                            const int* e2s, const int* e2d, const int* a01, const int* a12,
                            const int* cs, const int* cd, int* __restrict__ cur,
                            int* col0, int* col1, int* col2, int* colA01, int* colA12, int* colC) {
    int bb = blockIdx.x; const int* src; const int* dst; int nE, lb; int* cu; int* col;
    if (bb < HB1)      { src = e0s; dst = e0d; nE = E0;    cu = cur + U0; col = col0;   lb = bb; }
    else if (bb < HB2) { src = e1s; dst = e1d; nE = E1;    cu = cur + U1; col = col1;   lb = bb - HB1; }
    else if (bb < HB3) { src = e2s; dst = e2d; nE = E2;    cu = cur + U2; col = col2;   lb = bb - HB2; }
    else if (bb < HB4) { src = nullptr; dst = a01; nE = N0; cu = cur + U3; col = colA01; lb = bb - HB3; }
    else if (bb < HB5) { src = nullptr; dst = a12; nE = N1; cu = cur + U4; col = colA12; lb = bb - HB4; }
    else               { src = cs;  dst = cd;  nE = ECONN; cu = cur + U5; col = colC;   lb = bb - HB5; }
    int t = lb * 256 + threadIdx.x;
    if (t >= nE) return;
    int pos = atomicAdd(&cu[dst[t]], 1);
    col[pos] = src ? src[t] : t;
}

// ===== batched fused SAGE: h = tanh(x@Ws + mean_neigh(x)@Wn + b) =====
// 512 thr = 8 waves; 64 nodes/block, 8 nodes/wave (wave-private phase A, no barrier);
// phase B: weights read once per chunk, applied to all 8 nodes (acc[8] per lane).

template<int DIN, int DOUT>
__global__ __launch_bounds__(512) void sage_b(const float* __restrict__ x,
                       const int* __restrict__ rp, const int* __restrict__ col,
                       const float* __restrict__ Ws, const float* __restrict__ Wn,
                       const float* __restrict__ bias, float* __restrict__ h, int n) {
    constexpr int NW   = 8;          // nodes per wave
    constexpr int NPB  = 64;         // nodes per block
    constexpr int L4   = DIN / 4;    // lanes covering a row as float4
    constexpr int EPA  = 64 / L4;    // edges in flight per node (phase A)
    constexpr int SD   = DIN + 4;    // padded LDS stride
    constexpr int NPAR = 64 / DOUT;  // nodes computed in parallel per slot (phase B)
    constexpr int NSLOT = NW / NPAR;
    __shared__ float wsT[DOUT * SD];
    __shared__ float wnT[DOUT * SD];
    __shared__ float bs[DOUT];
    __shared__ float xsh[NPB][SD];
    __shared__ float msh[NPB][SD];
    // stage weights (issued early; conflicted writes amortized over 64 nodes)
    for (int idx = threadIdx.x; idx < DIN * DOUT; idx += 512) {
        int i = idx / DOUT, j = idx % DOUT;
        wsT[j * SD + i] = Ws[idx];
        wnT[j * SD + i] = Wn[idx];
    }
    if (threadIdx.x < DOUT) bs[threadIdx.x] = bias[threadIdx.x];
    const int wave = threadIdx.x >> 6;
    const int lane = threadIdx.x & 63;
    const int rowlane = lane % L4;
    const int esub = lane / L4;
    const int blockBase = blockIdx.x * NPB;
    // ---- phase A: per-wave gather of its 8 nodes ----
#pragma unroll
    for (int k = 0; k < NW; ++k) {
        int kk = wave * NW + k;
        int node = blockBase + kk;           // grids are exact multiples of 64
        int beg = rp[node], end = rp[node + 1];
        float4 own;
        if (lane < L4)
            own = *reinterpret_cast<const float4*>(&x[(size_t)node * DIN + lane * 4]);
        float4 s = make_float4(0.f, 0.f, 0.f, 0.f);
#pragma unroll 2
        for (int e = beg + esub; e < end; e += EPA) {
            int c = col[e];
            const float4 v = *reinterpret_cast<const float4*>(&x[(size_t)c * DIN + rowlane * 4]);
            s.x += v.x; s.y += v.y; s.z += v.z; s.w += v.w;
        }
#pragma unroll
        for (int m = L4; m < 64; m <<= 1) {
            s.x += __shfl_xor(s.x, m, 64);
            s.y += __shfl_xor(s.y, m, 64);
            s.z += __shfl_xor(s.z, m, 64);
            s.w += __shfl_xor(s.w, m, 64);
        }
        if (lane < L4) {
            float sc = (end > beg) ? 1.0f / (float)(end - beg) : 0.f;
            *reinterpret_cast<float4*>(&msh[kk][lane * 4]) =
                make_float4(s.x * sc, s.y * sc, s.z * sc, s.w * sc);
            *reinterpret_cast<float4*>(&xsh[kk][lane * 4]) = own;
        }
    }
    __syncthreads();   // weights staged + (wave-local) node data visible
    // ---- phase B: batched dense epilogue ----
    const int sub = lane / DOUT;   // 0..NPAR-1
    const int j = lane % DOUT;
    float acc[NSLOT];
#pragma unroll
    for (int sl = 0; sl < NSLOT; ++sl) acc[sl] = bs[j];
    for (int i = 0; i < DIN; i += 4) {
        const float4 w4 = *reinterpret_cast<const float4*>(&wsT[j * SD + i]);
        const float4 n4 = *reinterpret_cast<const float4*>(&wnT[j * SD + i]);
#pragma unroll
        for (int sl = 0; sl < NSLOT; ++sl) {
            int kk = wave * NW + sl * NPAR + sub;
            const float4 xv = *reinterpret_cast<const float4*>(&xsh[kk][i]);
            const float4 mv = *reinterpret_cast<const float4*>(&msh[kk][i]);
            acc[sl] += xv.x * w4.x + xv.y * w4.y + xv.z * w4.z + xv.w * w4.w
                     + mv.x * n4.x + mv.y * n4.y + mv.z * n4.z + mv.w * n4.w;
        }
    }
#pragma unroll
    for (int sl = 0; sl < NSLOT; ++sl) {
        int kk = wave * NW + sl * NPAR + sub;
        h[(size_t)(blockBase + kk) * DOUT + j] = tanhf(acc[sl]);
    }
}

// ===== pooling mean via CSR gather (F=32, 32 lanes/segment) =====

template<int F>
__global__ void csr_mean(const float* __restrict__ x, const int* __restrict__ rp,
                         const int* __restrict__ col, float* __restrict__ out, int n) {
    constexpr int G = 32, L4 = F / 4, EP = G / L4;
    int g = threadIdx.x / G, tg = threadIdx.x % G;
    int rowlane = tg % L4, esub = tg / L4;
    int seg = blockIdx.x * (256 / G) + g;
    if (seg >= n) return;
    int beg = rp[seg], end = rp[seg + 1];
    float4 s = make_float4(0.f, 0.f, 0.f, 0.f);
    for (int e = beg + esub; e < end; e += EP) {
        int c = col[e];
        const float4 v = *reinterpret_cast<const float4*>(&x[(size_t)c * F + rowlane * 4]);
        s.x += v.x; s.y += v.y; s.z += v.z; s.w += v.w;
    }
#pragma unroll
    for (int m = L4; m < G; m <<= 1) {
        s.x += __shfl_xor(s.x, m, 64);
        s.y += __shfl_xor(s.y, m, 64);
        s.z += __shfl_xor(s.z, m, 64);
        s.w += __shfl_xor(s.w, m, 64);
    }
    if (esub == 0) {
        float sc = (end > beg) ? 1.0f / (float)(end - beg) : 0.f;
        *reinterpret_cast<float4*>(&out[(size_t)seg * F + rowlane * 4]) =
            make_float4(s.x * sc, s.y * sc, s.z * sc, s.w * sc);
    }
}

// ===== cat[n] = [hup[assign[n]] (32) , hlo[n] (32)], float4 =====

__global__ void concat_kernel(const float* __restrict__ hup, const int* __restrict__ assign,
                              const float* __restrict__ hlo, float* __restrict__ cat, int n) {
    int t = blockIdx.x * blockDim.x + threadIdx.x; // over n*16 float4s
    if (t >= n * 16) return;
    int node = t >> 4, c = t & 15;
    float4 v;
    if (c < 8) v = *reinterpret_cast<const float4*>(&hup[(size_t)assign[node] * 32 + c * 4]);
    else       v = *reinterpret_cast<const float4*>(&hlo[(size_t)node * 32 + (c - 8) * 4]);
    *reinterpret_cast<float4*>(&cat[(size_t)t * 4]) = v;
}

// ===== fused conn-max + MLP: one wave per net, 4 net-rounds per block =====

__global__ __launch_bounds__(512) void mlp_kernel(const float* __restrict__ h0b,
                           const int* __restrict__ rp, const int* __restrict__ col,
                           const float* __restrict__ xnet,
                           const float* __restrict__ w1, const float* __restrict__ b1,
                           const float* __restrict__ w2, const float* __restrict__ b2,
                           float* __restrict__ out) {
    constexpr int SD = 84;
    __shared__ float w1T[64 * SD];
    __shared__ float w2s[64];
    __shared__ float xin[8][SD];
    for (int idx = threadIdx.x; idx < 80 * 64; idx += 512) {
        int i = idx / 64, j = idx % 64;
        w1T[j * SD + i] = w1[idx];
    }
    if (threadIdx.x < 64) w2s[threadIdx.x] = w2[threadIdx.x];
    __syncthreads();
    int wv = threadIdx.x >> 6;
    int lane = threadIdx.x & 63;
    int rowlane = lane & 15, esub = lane >> 4;
    for (int r = 0; r < 4; ++r) {
        int net = blockIdx.x * 32 + r * 8 + wv; // NNET == 6250*32
        int beg = rp[net], end = rp[net + 1];
        float4 m = make_float4(-INFINITY, -INFINITY, -INFINITY, -INFINITY);
        for (int e = beg + esub; e < end; e += 4) {
            int c = col[e];
            const float4 v = *reinterpret_cast<const float4*>(&h0b[(size_t)c * 64 + rowlane * 4]);
            m.x = fmaxf(m.x, v.x); m.y = fmaxf(m.y, v.y);
            m.z = fmaxf(m.z, v.z); m.w = fmaxf(m.w, v.w);
        }
#pragma unroll
        for (int msk = 16; msk < 64; msk <<= 1) {
            m.x = fmaxf(m.x, __shfl_xor(m.x, msk, 64));
            m.y = fmaxf(m.y, __shfl_xor(m.y, msk, 64));
            m.z = fmaxf(m.z, __shfl_xor(m.z, msk, 64));
            m.w = fmaxf(m.w, __shfl_xor(m.w, msk, 64));
        }
        if (beg == end) m = make_float4(0.f, 0.f, 0.f, 0.f);
        if (esub == 0) *reinterpret_cast<float4*>(&xin[wv][rowlane * 4]) = m;
        else if (esub == 1) xin[wv][64 + rowlane] = xnet[(size_t)net * 16 + rowlane];
        float acc = b1[lane];
#pragma unroll
        for (int i = 0; i < 80; i += 4) {
            const float4 w4 = *reinterpret_cast<const float4*>(&w1T[lane * SD + i]);
            const float4 xv = *reinterpret_cast<const float4*>(&xin[wv][i]);
            acc += xv.x * w4.x + xv.y * w4.y + xv.z * w4.z + xv.w * w4.w;
        }
        float p = tanhf(acc) * w2s[lane];
#pragma unroll
        for (int off = 32; off > 0; off >>= 1) p += __shfl_down(p, off, 64);
        if (lane == 0) out[net] = p + b2[0];
    }
}

// ===== host =====

extern "C" void kernel_launch(void* const* d_in, const int* in_sizes, int n_in,
                              void* d_out, int out_size, void* d_ws, size_t ws_size,
                              hipStream_t stream) {
    (void)in_sizes; (void)n_in; (void)out_size; (void)ws_size;
    const float* x0   = (const float*)d_in[0];
    const float* xnet = (const float*)d_in[1];
    const float* Ws0 = (const float*)d_in[2];  const float* Wn0 = (const float*)d_in[3];  const float* b0 = (const float*)d_in[4];
    const float* Ws1 = (const float*)d_in[5];  const float* Wn1 = (const float*)d_in[6];  const float* b1 = (const float*)d_in[7];
    const float* Ws2 = (const float*)d_in[8];  const float* Wn2 = (const float*)d_in[9];  const float* b2 = (const float*)d_in[10];
    const float* Ws3 = (const float*)d_in[11]; const float* Wn3 = (const float*)d_in[12]; const float* b3 = (const float*)d_in[13];
    const float* Ws4 = (const float*)d_in[14]; const float* Wn4 = (const float*)d_in[15]; const float* b4 = (const float*)d_in[16];
    const float* mw1 = (const float*)d_in[17]; const float* mb1 = (const float*)d_in[18];
    const float* mw2 = (const float*)d_in[19]; const float* mb2 = (const float*)d_in[20];
    const int* e0s = (const int*)d_in[21]; const int* e0d = (const int*)d_in[22];
    const int* e1s = (const int*)d_in[23]; const int* e1d = (const int*)d_in[24];
    const int* e2s = (const int*)d_in[25]; const int* e2d = (const int*)d_in[26];
    const int* a01 = (const int*)d_in[27]; const int* a12 = (const int*)d_in[28];
    const int* cs  = (const int*)d_in[29]; const int* cd  = (const int*)d_in[30];

    char* ws = (char*)d_ws;
    const size_t MB = 1u << 20;
    int* rp0    = (int*)(ws + (size_t)(0.00 * MB));
    int* col0   = (int*)(ws + (size_t)(1.25 * MB));
    int* rp1    = (int*)(ws + (size_t)(9.25 * MB));
    int* col1   = (int*)(ws + (size_t)(9.75 * MB));
    int* rp2    = (int*)(ws + (size_t)(11.75 * MB));
    int* col2   = (int*)(ws + (size_t)(12.00 * MB));
    int* rpA01  = (int*)(ws + (size_t)(12.50 * MB));
    int* colA01 = (int*)(ws + (size_t)(13.00 * MB));
    int* rpA12  = (int*)(ws + (size_t)(14.00 * MB));
    int* colA12 = (int*)(ws + (size_t)(14.25 * MB));
    int* rpC    = (int*)(ws + (size_t)(14.50 * MB));
    int* colC   = (int*)(ws + (size_t)(15.50 * MB));
    int* cnt    = (int*)(ws + (size_t)(18.75 * MB));   // CNT_TOT ints (2.51MB)
    int* cursor = (int*)(ws + (size_t)(21.50 * MB));   // 625984 ints (2.51MB)
    int* partials = (int*)(ws + (size_t)(24.25 * MB)); // STOT ints
    float* h0   = (float*)(ws + 25 * MB);   // 32MB -> 57
    float* h1   = (float*)(ws + 57 * MB);   // 8MB  -> 65
    float* h2   = (float*)(ws + 65 * MB);   // 2MB  -> 67
    float* x1   = (float*)(ws + 67 * MB);   // 8MB  -> 75
    float* x2   = (float*)(ws + 75 * MB);   // 2MB  -> 77
    float* cat1 = (float*)(ws + 77 * MB);   // 16MB -> 93 (dead before h0b written)
    float* h1b  = (float*)(ws + 93 * MB);   // 8MB  -> 101
    float* cat0 = (float*)(ws + 101 * MB);  // 64MB -> 165
    float* h0b  = (float*)(ws + 25 * MB);   // 64MB -> 89, aliases h0..cat1 (all dead)

    auto g = [](long n, int b) { return dim3((unsigned)((n + b - 1) / b)); };

    // ---- consolidated CSR build: 1 memset + 5 kernels ----
    hipMemsetAsync(cnt, 0, (size_t)CNT_TOT * 4, stream);
    hist_all<<<dim3(HTOT), 256, 0, stream>>>(e0d, e1d, e2d, a01, a12, cd, cnt);
    scan1_all<<<dim3(STOT), 256, 0, stream>>>(cnt, rp0, rp1, rp2, rpA01, rpA12, rpC, partials);
    scan2_all<<<dim3(6), 256, 0, stream>>>(partials);
    scan3_all<<<dim3(STOT), 256, 0, stream>>>(rp0, rp1, rp2, rpA01, rpA12, rpC, partials, cursor);
    scatter_all<<<dim3(HTOT), 256, 0, stream>>>(e0s, e0d, e1s, e1d, e2s, e2d, a01, a12, cs, cd,
                                                cursor, col0, col1, col2, colA01, colA12, colC);

    // ---- layer 0: h0 = sage(x0, e0)  [N0,32]
    sage_b<16, 32><<<dim3(N0 / 64), 512, 0, stream>>>(x0, rp0, col0, Ws0, Wn0, b0, h0, N0);
    // ---- pool 0->1: x1 = seg_mean(h0, assign01)  [N1,32]
    csr_mean<32><<<dim3(N1 / 8), 256, 0, stream>>>(h0, rpA01, colA01, x1, N1);
    // ---- layer 1: h1 = sage(x1, e1)  [N1,32]
    sage_b<32, 32><<<dim3(N1 / 64), 512, 0, stream>>>(x1, rp1, col1, Ws1, Wn1, b1, h1, N1);
    // ---- pool 1->2: x2 = seg_mean(h1, assign12)  [N2,32]
    csr_mean<32><<<dim3(N2 / 8), 256, 0, stream>>>(h1, rpA12, colA12, x2, N2);
    // ---- layer 2: h2 = sage(x2, e2)  [N2,32]
    sage_b<32, 32><<<dim3(N2 / 64), 512, 0, stream>>>(x2, rp2, col2, Ws2, Wn2, b2, h2, N2);
    // ---- up 2->1: cat1 = [h2[assign12], h1]; h1b = sage(cat1, e1)  [N1,32]
    concat_kernel<<<g((long)N1 * 16, 256), 256, 0, stream>>>(h2, a12, h1, cat1, N1);
    sage_b<64, 32><<<dim3(N1 / 64), 512, 0, stream>>>(cat1, rp1, col1, Ws3, Wn3, b3, h1b, N1);
    // ---- up 1->0: cat0 = [h1b[assign01], h0]; h0b = sage(cat0, e0)  [N0,64]
    concat_kernel<<<g((long)N0 * 16, 256), 256, 0, stream>>>(h1b, a01, h0, cat0, N0);
    sage_b<64, 64><<<dim3(N0 / 64), 512, 0, stream>>>(cat0, rp0, col0, Ws4, Wn4, b4, h0b, N0);
    // ---- fused per-net segment-max + MLP -> out [NNET,1]
    mlp_kernel<<<dim3(NNET / 32), 512, 0, stream>>>(h0b, rpC, colC, xnet, mw1, mb1, mw2, mb2,
                                                    (float*)d_out);
}

// Round 5
// 826.649 us; speedup vs baseline: 1.4439x; 1.4439x over previous
//
#include <hip/hip_runtime.h>

#define N0 262144
#define N1 65536
#define N2 16384
#define NNET 200000
#define E0 2097152
#define E1 524288
#define E2 131072
#define ECONN 800000

// ===== binned CSR build =====
// bucket = 1024 consecutive node ids (shift BSH). 6 lists -> 612 global buckets.
// bin[] / colAll[] are single arenas; list l's slice starts at BB[l]:
//   l:    0(e0)    1(e1)    2(e2)    3(a01)   4(a12)   5(conn)
//   GB:   0        256      320      336      400      416     (tot 612)
//   EDG:  E0       E1       E2       N0       N1       ECONN   (tot 3880192)
//   NSEG: N0       N1       N2       N1       N2       NNET
#define BSH 10
#define NBK_TOT 612
#define CHK 16384
#define CBT 237   // chunk blocks: 128+32+8+16+4+49

__global__ void bcount(const int* __restrict__ e0d, const int* __restrict__ e1d,
                       const int* __restrict__ e2d, const int* __restrict__ a01,
                       const int* __restrict__ a12, const int* __restrict__ cd,
                       int* __restrict__ bcnt) {
    int bb = blockIdx.x; int lb, nE, nbuk, gb; const int* dst;
    if (bb < 128)      { lb=bb;     dst=e0d; nE=E0;    nbuk=256; gb=0; }
    else if (bb < 160) { lb=bb-128; dst=e1d; nE=E1;    nbuk=64;  gb=256; }
    else if (bb < 168) { lb=bb-160; dst=e2d; nE=E2;    nbuk=16;  gb=320; }
    else if (bb < 184) { lb=bb-168; dst=a01; nE=N0;    nbuk=64;  gb=336; }
    else if (bb < 188) { lb=bb-184; dst=a12; nE=N1;    nbuk=16;  gb=400; }
    else               { lb=bb-188; dst=cd;  nE=ECONN; nbuk=196; gb=416; }
    __shared__ int h[256];
    for (int i = threadIdx.x; i < nbuk; i += 256) h[i] = 0;
    __syncthreads();
    int base = lb * CHK;
    for (int k = 0; k < CHK / 256; ++k) {
        int e = base + k * 256 + threadIdx.x;
        if (e < nE) atomicAdd(&h[dst[e] >> BSH], 1);
    }
    __syncthreads();
    for (int i = threadIdx.x; i < nbuk; i += 256)
        if (h[i]) atomicAdd(&bcnt[gb + i], h[i]);
}

__global__ __launch_bounds__(1024) void bscan(const int* __restrict__ bcnt,
                                              int* __restrict__ bs, int* __restrict__ cur) {
    __shared__ int ts[1024];
    int t = threadIdx.x;
    int v = (t < NBK_TOT) ? bcnt[t] : 0;
    ts[t] = v; __syncthreads();
    for (int off = 1; off < 1024; off <<= 1) {
        int u = (t >= off) ? ts[t - off] : 0; __syncthreads();
        ts[t] += u; __syncthreads();
    }
    if (t < NBK_TOT) {
        int ex = ts[t] - v;
        bs[t] = ex; cur[t] = ex;
        if (t == NBK_TOT - 1) bs[NBK_TOT] = ts[t];
    }
}

__global__ void bscatter(const int* e0s, const int* e0d, const int* e1s, const int* e1d,
                         const int* e2s, const int* e2d, const int* a01, const int* a12,
                         const int* cs, const int* cd,
                         int* __restrict__ cur, int2* __restrict__ bin) {
    int bb = blockIdx.x; int lb, nE, nbuk, gb; const int* dst; const int* src;
    if (bb < 128)      { lb=bb;     dst=e0d; src=e0s;     nE=E0;    nbuk=256; gb=0; }
    else if (bb < 160) { lb=bb-128; dst=e1d; src=e1s;     nE=E1;    nbuk=64;  gb=256; }
    else if (bb < 168) { lb=bb-160; dst=e2d; src=e2s;     nE=E2;    nbuk=16;  gb=320; }
    else if (bb < 184) { lb=bb-168; dst=a01; src=nullptr; nE=N0;    nbuk=64;  gb=336; }
    else if (bb < 188) { lb=bb-184; dst=a12; src=nullptr; nE=N1;    nbuk=16;  gb=400; }
    else               { lb=bb-188; dst=cd;  src=cs;      nE=ECONN; nbuk=196; gb=416; }
    __shared__ int h[256];
    __shared__ int curl[256];
    for (int i = threadIdx.x; i < nbuk; i += 256) h[i] = 0;
    __syncthreads();
    int base = lb * CHK;
    for (int k = 0; k < CHK / 256; ++k) {
        int e = base + k * 256 + threadIdx.x;
        if (e < nE) atomicAdd(&h[dst[e] >> BSH], 1);
    }
    __syncthreads();
    for (int i = threadIdx.x; i < nbuk; i += 256)
        if (h[i]) curl[i] = atomicAdd(&cur[gb + i], h[i]);
    __syncthreads();
    for (int k = 0; k < CHK / 256; ++k) {
        int e = base + k * 256 + threadIdx.x;
        if (e < nE) {
            int d = dst[e];
            int pos = atomicAdd(&curl[d >> BSH], 1);
            bin[pos] = make_int2(d, src ? src[e] : e);
        }
    }
}

// one block per bucket: LDS per-node hist + scan -> dense rp write + windowed col scatter
__global__ __launch_bounds__(512) void bbuild(const int2* __restrict__ bin,
                        const int* __restrict__ bs, int* __restrict__ colAll,
                        int* rp0, int* rp1, int* rp2, int* rpA01, int* rpA12, int* rpC) {
    int g = blockIdx.x; int lb, nSeg, last; int* rp;
    if (g < 256)      { lb=g;     nSeg=N0;   rp=rp0;   last=(g==255); }
    else if (g < 320) { lb=g-256; nSeg=N1;   rp=rp1;   last=(g==319); }
    else if (g < 336) { lb=g-320; nSeg=N2;   rp=rp2;   last=(g==335); }
    else if (g < 400) { lb=g-336; nSeg=N1;   rp=rpA01; last=(g==399); }
    else if (g < 416) { lb=g-400; nSeg=N2;   rp=rpA12; last=(g==415); }
    else              { lb=g-416; nSeg=NNET; rp=rpC;   last=(g==611); }
    const int nodeBase = lb << BSH;
    const int begE = bs[g], endE = bs[g + 1];
    __shared__ int cnt[1024];
    __shared__ int rpl[1024];
    __shared__ int ts[512];
    const int t = threadIdx.x;
    cnt[t] = 0; cnt[t + 512] = 0;
    __syncthreads();
    for (int e = begE + t; e < endE; e += 512)
        atomicAdd(&cnt[bin[e].x - nodeBase], 1);
    __syncthreads();
    int a = cnt[2 * t], b = cnt[2 * t + 1];
    int s = a + b;
    ts[t] = s; __syncthreads();
    for (int off = 1; off < 512; off <<= 1) {
        int u = (t >= off) ? ts[t - off] : 0; __syncthreads();
        ts[t] += u; __syncthreads();
    }
    int pre = ts[t] - s;
    rpl[2 * t] = pre; rpl[2 * t + 1] = pre + a;
    __syncthreads();
    int lim = nSeg - nodeBase; if (lim > 1024) lim = 1024;
    for (int i = t; i < lim; i += 512) {
        int abs0 = begE + rpl[i];
        rp[nodeBase + i] = abs0;
        cnt[i] = abs0;            // becomes absolute cursor
    }
    if (last && t == 0) rp[nSeg] = endE;
    __syncthreads();
    for (int e = begE + t; e < endE; e += 512) {
        int2 p = bin[e];
        int pos = atomicAdd(&cnt[p.x - nodeBase], 1);
        colAll[pos] = p.y;
    }
}

// ===== batched fused SAGE: h = tanh(x@Ws + mean_neigh(x)@Wn + b) =====

template<int DIN, int DOUT>
__global__ __launch_bounds__(512) void sage_b(const float* __restrict__ x,
                       const int* __restrict__ rp, const int* __restrict__ col,
                       const float* __restrict__ Ws, const float* __restrict__ Wn,
                       const float* __restrict__ bias, float* __restrict__ h, int n) {
    constexpr int NW   = 8;
    constexpr int NPB  = 64;
    constexpr int L4   = DIN / 4;
    constexpr int EPA  = 64 / L4;
    constexpr int SD   = DIN + 4;
    constexpr int NPAR = 64 / DOUT;
    constexpr int NSLOT = NW / NPAR;
    __shared__ float wsT[DOUT * SD];
    __shared__ float wnT[DOUT * SD];
    __shared__ float bs_[DOUT];
    __shared__ float xsh[NPB][SD];
    __shared__ float msh[NPB][SD];
    for (int idx = threadIdx.x; idx < DIN * DOUT; idx += 512) {
        int i = idx / DOUT, j = idx % DOUT;
        wsT[j * SD + i] = Ws[idx];
        wnT[j * SD + i] = Wn[idx];
    }
    if (threadIdx.x < DOUT) bs_[threadIdx.x] = bias[threadIdx.x];
    const int wave = threadIdx.x >> 6;
    const int lane = threadIdx.x & 63;
    const int rowlane = lane % L4;
    const int esub = lane / L4;
    const int blockBase = blockIdx.x * NPB;
#pragma unroll
    for (int k = 0; k < NW; ++k) {
        int kk = wave * NW + k;
        int node = blockBase + kk;
        int beg = rp[node], end = rp[node + 1];
        float4 own;
        if (lane < L4)
            own = *reinterpret_cast<const float4*>(&x[(size_t)node * DIN + lane * 4]);
        float4 s = make_float4(0.f, 0.f, 0.f, 0.f);
#pragma unroll 2
        for (int e = beg + esub; e < end; e += EPA) {
            int c = col[e];
            const float4 v = *reinterpret_cast<const float4*>(&x[(size_t)c * DIN + rowlane * 4]);
            s.x += v.x; s.y += v.y; s.z += v.z; s.w += v.w;
        }
#pragma unroll
        for (int m = L4; m < 64; m <<= 1) {
            s.x += __shfl_xor(s.x, m, 64);
            s.y += __shfl_xor(s.y, m, 64);
            s.z += __shfl_xor(s.z, m, 64);
            s.w += __shfl_xor(s.w, m, 64);
        }
        if (lane < L4) {
            float sc = (end > beg) ? 1.0f / (float)(end - beg) : 0.f;
            *reinterpret_cast<float4*>(&msh[kk][lane * 4]) =
                make_float4(s.x * sc, s.y * sc, s.z * sc, s.w * sc);
            *reinterpret_cast<float4*>(&xsh[kk][lane * 4]) = own;
        }
    }
    __syncthreads();
    const int sub = lane / DOUT;
    const int j = lane % DOUT;
    float acc[NSLOT];
#pragma unroll
    for (int sl = 0; sl < NSLOT; ++sl) acc[sl] = bs_[j];
    for (int i = 0; i < DIN; i += 4) {
        const float4 w4 = *reinterpret_cast<const float4*>(&wsT[j * SD + i]);
        const float4 n4 = *reinterpret_cast<const float4*>(&wnT[j * SD + i]);
#pragma unroll
        for (int sl = 0; sl < NSLOT; ++sl) {
            int kk = wave * NW + sl * NPAR + sub;
            const float4 xv = *reinterpret_cast<const float4*>(&xsh[kk][i]);
            const float4 mv = *reinterpret_cast<const float4*>(&msh[kk][i]);
            acc[sl] += xv.x * w4.x + xv.y * w4.y + xv.z * w4.z + xv.w * w4.w
                     + mv.x * n4.x + mv.y * n4.y + mv.z * n4.z + mv.w * n4.w;
        }
    }
#pragma unroll
    for (int sl = 0; sl < NSLOT; ++sl) {
        int kk = wave * NW + sl * NPAR + sub;
        h[(size_t)(blockBase + kk) * DOUT + j] = tanhf(acc[sl]);
    }
}

// ===== pooling mean via CSR gather =====

template<int F>
__global__ void csr_mean(const float* __restrict__ x, const int* __restrict__ rp,
                         const int* __restrict__ col, float* __restrict__ out, int n) {
    constexpr int G = 32, L4 = F / 4, EP = G / L4;
    int g = threadIdx.x / G, tg = threadIdx.x % G;
    int rowlane = tg % L4, esub = tg / L4;
    int seg = blockIdx.x * (256 / G) + g;
    if (seg >= n) return;
    int beg = rp[seg], end = rp[seg + 1];
    float4 s = make_float4(0.f, 0.f, 0.f, 0.f);
    for (int e = beg + esub; e < end; e += EP) {
        int c = col[e];
        const float4 v = *reinterpret_cast<const float4*>(&x[(size_t)c * F + rowlane * 4]);
        s.x += v.x; s.y += v.y; s.z += v.z; s.w += v.w;
    }
#pragma unroll
    for (int m = L4; m < G; m <<= 1) {
        s.x += __shfl_xor(s.x, m, 64);
        s.y += __shfl_xor(s.y, m, 64);
        s.z += __shfl_xor(s.z, m, 64);
        s.w += __shfl_xor(s.w, m, 64);
    }
    if (esub == 0) {
        float sc = (end > beg) ? 1.0f / (float)(end - beg) : 0.f;
        *reinterpret_cast<float4*>(&out[(size_t)seg * F + rowlane * 4]) =
            make_float4(s.x * sc, s.y * sc, s.z * sc, s.w * sc);
    }
}

// ===== cat[n] = [hup[assign[n]] (32) , hlo[n] (32)], float4 =====

__global__ void concat_kernel(const float* __restrict__ hup, const int* __restrict__ assign,
                              const float* __restrict__ hlo, float* __restrict__ cat, int n) {
    int t = blockIdx.x * blockDim.x + threadIdx.x;
    if (t >= n * 16) return;
    int node = t >> 4, c = t & 15;
    float4 v;
    if (c < 8) v = *reinterpret_cast<const float4*>(&hup[(size_t)assign[node] * 32 + c * 4]);
    else       v = *reinterpret_cast<const float4*>(&hlo[(size_t)node * 32 + (c - 8) * 4]);
    *reinterpret_cast<float4*>(&cat[(size_t)t * 4]) = v;
}

// ===== fused conn-max + MLP =====

__global__ __launch_bounds__(512) void mlp_kernel(const float* __restrict__ h0b,
                           const int* __restrict__ rp, const int* __restrict__ col,
                           const float* __restrict__ xnet,
                           const float* __restrict__ w1, const float* __restrict__ b1,
                           const float* __restrict__ w2, const float* __restrict__ b2,
                           float* __restrict__ out) {
    constexpr int SD = 84;
    __shared__ float w1T[64 * SD];
    __shared__ float w2s[64];
    __shared__ float xin[8][SD];
    for (int idx = threadIdx.x; idx < 80 * 64; idx += 512) {
        int i = idx / 64, j = idx % 64;
        w1T[j * SD + i] = w1[idx];
    }
    if (threadIdx.x < 64) w2s[threadIdx.x] = w2[threadIdx.x];
    __syncthreads();
    int wv = threadIdx.x >> 6;
    int lane = threadIdx.x & 63;
    int rowlane = lane & 15, esub = lane >> 4;
    for (int r = 0; r < 4; ++r) {
        int net = blockIdx.x * 32 + r * 8 + wv;
        int beg = rp[net], end = rp[net + 1];
        float4 m = make_float4(-INFINITY, -INFINITY, -INFINITY, -INFINITY);
        for (int e = beg + esub; e < end; e += 4) {
            int c = col[e];
            const float4 v = *reinterpret_cast<const float4*>(&h0b[(size_t)c * 64 + rowlane * 4]);
            m.x = fmaxf(m.x, v.x); m.y = fmaxf(m.y, v.y);
            m.z = fmaxf(m.z, v.z); m.w = fmaxf(m.w, v.w);
        }
#pragma unroll
        for (int msk = 16; msk < 64; msk <<= 1) {
            m.x = fmaxf(m.x, __shfl_xor(m.x, msk, 64));
            m.y = fmaxf(m.y, __shfl_xor(m.y, msk, 64));
            m.z = fmaxf(m.z, __shfl_xor(m.z, msk, 64));
            m.w = fmaxf(m.w, __shfl_xor(m.w, msk, 64));
        }
        if (beg == end) m = make_float4(0.f, 0.f, 0.f, 0.f);
        if (esub == 0) *reinterpret_cast<float4*>(&xin[wv][rowlane * 4]) = m;
        else if (esub == 1) xin[wv][64 + rowlane] = xnet[(size_t)net * 16 + rowlane];
        float acc = b1[lane];
#pragma unroll
        for (int i = 0; i < 80; i += 4) {
            const float4 w4 = *reinterpret_cast<const float4*>(&w1T[lane * SD + i]);
            const float4 xv = *reinterpret_cast<const float4*>(&xin[wv][i]);
            acc += xv.x * w4.x + xv.y * w4.y + xv.z * w4.z + xv.w * w4.w;
        }
        float p = tanhf(acc) * w2s[lane];
#pragma unroll
        for (int off = 32; off > 0; off >>= 1) p += __shfl_down(p, off, 64);
        if (lane == 0) out[net] = p + b2[0];
    }
}

// ===== host =====

extern "C" void kernel_launch(void* const* d_in, const int* in_sizes, int n_in,
                              void* d_out, int out_size, void* d_ws, size_t ws_size,
                              hipStream_t stream) {
    (void)in_sizes; (void)n_in; (void)out_size; (void)ws_size;
    const float* x0   = (const float*)d_in[0];
    const float* xnet = (const float*)d_in[1];
    const float* Ws0 = (const float*)d_in[2];  const float* Wn0 = (const float*)d_in[3];  const float* b0 = (const float*)d_in[4];
    const float* Ws1 = (const float*)d_in[5];  const float* Wn1 = (const float*)d_in[6];  const float* b1 = (const float*)d_in[7];
    const float* Ws2 = (const float*)d_in[8];  const float* Wn2 = (const float*)d_in[9];  const float* b2 = (const float*)d_in[10];
    const float* Ws3 = (const float*)d_in[11]; const float* Wn3 = (const float*)d_in[12]; const float* b3 = (const float*)d_in[13];
    const float* Ws4 = (const float*)d_in[14]; const float* Wn4 = (const float*)d_in[15]; const float* b4 = (const float*)d_in[16];
    const float* mw1 = (const float*)d_in[17]; const float* mb1 = (const float*)d_in[18];
    const float* mw2 = (const float*)d_in[19]; const float* mb2 = (const float*)d_in[20];
    const int* e0s = (const int*)d_in[21]; const int* e0d = (const int*)d_in[22];
    const int* e1s = (const int*)d_in[23]; const int* e1d = (const int*)d_in[24];
    const int* e2s = (const int*)d_in[25]; const int* e2d = (const int*)d_in[26];
    const int* a01 = (const int*)d_in[27]; const int* a12 = (const int*)d_in[28];
    const int* cs  = (const int*)d_in[29]; const int* cd  = (const int*)d_in[30];

    char* ws = (char*)d_ws;
    const size_t MB = 1u << 20;
    int* rp0    = (int*)(ws + (size_t)(0.00 * MB));     // 262145 ints
    int* rp1    = (int*)(ws + (size_t)(1.25 * MB));     // 65537
    int* rp2    = (int*)(ws + (size_t)(1.75 * MB));     // 16385
    int* rpA01  = (int*)(ws + (size_t)(2.00 * MB));     // 65537
    int* rpA12  = (int*)(ws + (size_t)(2.50 * MB));     // 16385
    int* rpC    = (int*)(ws + (size_t)(2.75 * MB));     // 200001
    int* bcnt   = (int*)(ws + (size_t)(3.75 * MB));            // 612
    int* bs     = (int*)(ws + (size_t)(3.75 * MB) + 4096);     // 613
    int* cur    = (int*)(ws + (size_t)(3.75 * MB) + 8192);     // 612
    int* colAll = (int*)(ws + (size_t)(4.00 * MB));     // 3880192 ints (14.8MB)
    float* h0   = (float*)(ws + 19 * MB);    // 32MB
    float* h1   = (float*)(ws + 51 * MB);    // 8MB
    float* h2   = (float*)(ws + 59 * MB);    // 2MB
    float* x1   = (float*)(ws + 61 * MB);    // 8MB
    float* x2   = (float*)(ws + 69 * MB);    // 2MB
    float* cat1 = (float*)(ws + 71 * MB);    // 16MB
    float* h1b  = (float*)(ws + 87 * MB);    // 8MB
    float* cat0 = (float*)(ws + 95 * MB);    // 64MB -> 159
    float* h0b  = (float*)(ws + 19 * MB);    // 64MB, aliases h0..cat1 (dead by then)
    int2* bin   = (int2*)(ws + 95 * MB);     // 31MB, dead before cat0 written

    auto g = [](long n, int b) { return dim3((unsigned)((n + b - 1) / b)); };

    // ---- binned CSR build: memset + 4 kernels, no fine-grained global atomics ----
    hipMemsetAsync(bcnt, 0, NBK_TOT * 4, stream);
    bcount<<<dim3(CBT), 256, 0, stream>>>(e0d, e1d, e2d, a01, a12, cd, bcnt);
    bscan<<<dim3(1), 1024, 0, stream>>>(bcnt, bs, cur);
    bscatter<<<dim3(CBT), 256, 0, stream>>>(e0s, e0d, e1s, e1d, e2s, e2d, a01, a12, cs, cd,
                                            cur, bin);
    bbuild<<<dim3(NBK_TOT), 512, 0, stream>>>(bin, bs, colAll,
                                              rp0, rp1, rp2, rpA01, rpA12, rpC);

    // ---- layer 0: h0 = sage(x0, e0)  [N0,32]
    sage_b<16, 32><<<dim3(N0 / 64), 512, 0, stream>>>(x0, rp0, colAll, Ws0, Wn0, b0, h0, N0);
    // ---- pool 0->1: x1 = seg_mean(h0, assign01)  [N1,32]
    csr_mean<32><<<dim3(N1 / 8), 256, 0, stream>>>(h0, rpA01, colAll, x1, N1);
    // ---- layer 1: h1 = sage(x1, e1)  [N1,32]
    sage_b<32, 32><<<dim3(N1 / 64), 512, 0, stream>>>(x1, rp1, colAll, Ws1, Wn1, b1, h1, N1);
    // ---- pool 1->2: x2 = seg_mean(h1, assign12)  [N2,32]
    csr_mean<32><<<dim3(N2 / 8), 256, 0, stream>>>(h1, rpA12, colAll, x2, N2);
    // ---- layer 2: h2 = sage(x2, e2)  [N2,32]
    sage_b<32, 32><<<dim3(N2 / 64), 512, 0, stream>>>(x2, rp2, colAll, Ws2, Wn2, b2, h2, N2);
    // ---- up 2->1: cat1 = [h2[assign12], h1]; h1b = sage(cat1, e1)  [N1,32]
    concat_kernel<<<g((long)N1 * 16, 256), 256, 0, stream>>>(h2, a12, h1, cat1, N1);
    sage_b<64, 32><<<dim3(N1 / 64), 512, 0, stream>>>(cat1, rp1, colAll, Ws3, Wn3, b3, h1b, N1);
    // ---- up 1->0: cat0 = [h1b[assign01], h0]; h0b = sage(cat0, e0)  [N0,64]
    concat_kernel<<<g((long)N0 * 16, 256), 256, 0, stream>>>(h1b, a01, h0, cat0, N0);
    sage_b<64, 64><<<dim3(N0 / 64), 512, 0, stream>>>(cat0, rp0, colAll, Ws4, Wn4, b4, h0b, N0);
    // ---- fused per-net segment-max + MLP -> out [NNET,1]
    mlp_kernel<<<dim3(NNET / 32), 512, 0, stream>>>(h0b, rpC, colAll, xnet, mw1, mb1, mw2, mb2,
                                                    (float*)d_out);
}

// Round 7
// 727.543 us; speedup vs baseline: 1.6406x; 1.1362x over previous
//
#include <hip/hip_runtime.h>

#define N0 262144
#define N1 65536
#define N2 16384
#define NNET 200000
#define E0 2097152
#define E1 524288
#define E2 131072
#define ECONN 800000

// ===== binned CSR build (unchanged from round 4) =====
#define BSH 10
#define NBK_TOT 612
#define CHK 16384
#define CBT 237

__global__ void bcount(const int* __restrict__ e0d, const int* __restrict__ e1d,
                       const int* __restrict__ e2d, const int* __restrict__ a01,
                       const int* __restrict__ a12, const int* __restrict__ cd,
                       int* __restrict__ bcnt) {
    int bb = blockIdx.x; int lb, nE, nbuk, gb; const int* dst;
    if (bb < 128)      { lb=bb;     dst=e0d; nE=E0;    nbuk=256; gb=0; }
    else if (bb < 160) { lb=bb-128; dst=e1d; nE=E1;    nbuk=64;  gb=256; }
    else if (bb < 168) { lb=bb-160; dst=e2d; nE=E2;    nbuk=16;  gb=320; }
    else if (bb < 184) { lb=bb-168; dst=a01; nE=N0;    nbuk=64;  gb=336; }
    else if (bb < 188) { lb=bb-184; dst=a12; nE=N1;    nbuk=16;  gb=400; }
    else               { lb=bb-188; dst=cd;  nE=ECONN; nbuk=196; gb=416; }
    __shared__ int h[256];
    for (int i = threadIdx.x; i < nbuk; i += 256) h[i] = 0;
    __syncthreads();
    int base = lb * CHK;
    for (int k = 0; k < CHK / 256; ++k) {
        int e = base + k * 256 + threadIdx.x;
        if (e < nE) atomicAdd(&h[dst[e] >> BSH], 1);
    }
    __syncthreads();
    for (int i = threadIdx.x; i < nbuk; i += 256)
        if (h[i]) atomicAdd(&bcnt[gb + i], h[i]);
}

__global__ __launch_bounds__(1024) void bscan(const int* __restrict__ bcnt,
                                              int* __restrict__ bs, int* __restrict__ cur) {
    __shared__ int ts[1024];
    int t = threadIdx.x;
    int v = (t < NBK_TOT) ? bcnt[t] : 0;
    ts[t] = v; __syncthreads();
    for (int off = 1; off < 1024; off <<= 1) {
        int u = (t >= off) ? ts[t - off] : 0; __syncthreads();
        ts[t] += u; __syncthreads();
    }
    if (t < NBK_TOT) {
        int ex = ts[t] - v;
        bs[t] = ex; cur[t] = ex;
        if (t == NBK_TOT - 1) bs[NBK_TOT] = ts[t];
    }
}

__global__ void bscatter(const int* e0s, const int* e0d, const int* e1s, const int* e1d,
                         const int* e2s, const int* e2d, const int* a01, const int* a12,
                         const int* cs, const int* cd,
                         int* __restrict__ cur, int2* __restrict__ bin) {
    int bb = blockIdx.x; int lb, nE, nbuk, gb; const int* dst; const int* src;
    if (bb < 128)      { lb=bb;     dst=e0d; src=e0s;     nE=E0;    nbuk=256; gb=0; }
    else if (bb < 160) { lb=bb-128; dst=e1d; src=e1s;     nE=E1;    nbuk=64;  gb=256; }
    else if (bb < 168) { lb=bb-160; dst=e2d; src=e2s;     nE=E2;    nbuk=16;  gb=320; }
    else if (bb < 184) { lb=bb-168; dst=a01; src=nullptr; nE=N0;    nbuk=64;  gb=336; }
    else if (bb < 188) { lb=bb-184; dst=a12; src=nullptr; nE=N1;    nbuk=16;  gb=400; }
    else               { lb=bb-188; dst=cd;  src=cs;      nE=ECONN; nbuk=196; gb=416; }
    __shared__ int h[256];
    __shared__ int curl[256];
    for (int i = threadIdx.x; i < nbuk; i += 256) h[i] = 0;
    __syncthreads();
    int base = lb * CHK;
    for (int k = 0; k < CHK / 256; ++k) {
        int e = base + k * 256 + threadIdx.x;
        if (e < nE) atomicAdd(&h[dst[e] >> BSH], 1);
    }
    __syncthreads();
    for (int i = threadIdx.x; i < nbuk; i += 256)
        if (h[i]) curl[i] = atomicAdd(&cur[gb + i], h[i]);
    __syncthreads();
    for (int k = 0; k < CHK / 256; ++k) {
        int e = base + k * 256 + threadIdx.x;
        if (e < nE) {
            int d = dst[e];
            int pos = atomicAdd(&curl[d >> BSH], 1);
            bin[pos] = make_int2(d, src ? src[e] : e);
        }
    }
}

__global__ __launch_bounds__(512) void bbuild(const int2* __restrict__ bin,
                        const int* __restrict__ bs, int* __restrict__ colAll,
                        int* rp0, int* rp1, int* rp2, int* rpA01, int* rpA12, int* rpC) {
    int g = blockIdx.x; int lb, nSeg, last; int* rp;
    if (g < 256)      { lb=g;     nSeg=N0;   rp=rp0;   last=(g==255); }
    else if (g < 320) { lb=g-256; nSeg=N1;   rp=rp1;   last=(g==319); }
    else if (g < 336) { lb=g-320; nSeg=N2;   rp=rp2;   last=(g==335); }
    else if (g < 400) { lb=g-336; nSeg=N1;   rp=rpA01; last=(g==399); }
    else if (g < 416) { lb=g-400; nSeg=N2;   rp=rpA12; last=(g==415); }
    else              { lb=g-416; nSeg=NNET; rp=rpC;   last=(g==611); }
    const int nodeBase = lb << BSH;
    const int begE = bs[g], endE = bs[g + 1];
    __shared__ int cnt[1024];
    __shared__ int rpl[1024];
    __shared__ int ts[512];
    const int t = threadIdx.x;
    cnt[t] = 0; cnt[t + 512] = 0;
    __syncthreads();
    for (int e = begE + t; e < endE; e += 512)
        atomicAdd(&cnt[bin[e].x - nodeBase], 1);
    __syncthreads();
    int a = cnt[2 * t], b = cnt[2 * t + 1];
    int s = a + b;
    ts[t] = s; __syncthreads();
    for (int off = 1; off < 512; off <<= 1) {
        int u = (t >= off) ? ts[t - off] : 0; __syncthreads();
        ts[t] += u; __syncthreads();
    }
    int pre = ts[t] - s;
    rpl[2 * t] = pre; rpl[2 * t + 1] = pre + a;
    __syncthreads();
    int lim = nSeg - nodeBase; if (lim > 1024) lim = 1024;
    for (int i = t; i < lim; i += 512) {
        int abs0 = begE + rpl[i];
        rp[nodeBase + i] = abs0;
        cnt[i] = abs0;
    }
    if (last && t == 0) rp[nSeg] = endE;
    __syncthreads();
    for (int e = begE + t; e < endE; e += 512) {
        int2 p = bin[e];
        int pos = atomicAdd(&cnt[p.x - nodeBase], 1);
        colAll[pos] = p.y;
    }
}

// ===== helpers =====
__device__ __forceinline__ void fma4(float4& a, float s, const float4& b) {
    a.x = fmaf(s, b.x, a.x); a.y = fmaf(s, b.y, a.y);
    a.z = fmaf(s, b.z, a.z); a.w = fmaf(s, b.w, a.w);
}
__device__ __forceinline__ void red4(float4& s, int m) {
    s.x += __shfl_xor(s.x, m, 64);
    s.y += __shfl_xor(s.y, m, 64);
    s.z += __shfl_xor(s.z, m, 64);
    s.w += __shfl_xor(s.w, m, 64);
}

// ===== fused SAGE, barrier-free: h = tanh(x@Ws + mean_neigh(x)@Wn + b) =====
// Phase A: wave gathers its 8 nodes (L4 lanes per row, EPA edges in flight),
// results to wave-private LDS rows. Phase B: j-quad layout, weights streamed
// from GLOBAL (L1-resident, coalesced b128 row reads); LDS only for x/mean
// broadcasts. No __syncthreads anywhere.

template<int DIN, int DOUT>
__global__ __launch_bounds__(512) void sage_b(const float* __restrict__ x,
                       const int* __restrict__ rp, const int* __restrict__ col,
                       const float* __restrict__ Ws, const float* __restrict__ Wn,
                       const float* __restrict__ bias, float* __restrict__ h, int n) {
    constexpr int NW  = 8;
    constexpr int NPB = 64;
    constexpr int L4  = DIN / 4;
    constexpr int EPA = 64 / L4;
    constexpr int SD  = DIN + 4;
    constexpr int JQ  = DOUT / 4;    // j-quads per row
    constexpr int NDP = 64 / JQ;     // nodes in parallel (phase B)
    constexpr int NSL = NW / NDP;    // slots
    __shared__ float xsh[NPB][SD];
    __shared__ float msh[NPB][SD];
    const int wave = threadIdx.x >> 6;
    const int lane = threadIdx.x & 63;
    const int rowlane = lane % L4;
    const int esub = lane / L4;
    const int blockBase = blockIdx.x * NPB;
    // ---- phase A ----
#pragma unroll
    for (int k = 0; k < NW; ++k) {
        const int kk = wave * NW + k;
        const int node = blockBase + kk;
        const int beg = rp[node], end = rp[node + 1];
        float4 own = make_float4(0.f, 0.f, 0.f, 0.f);
        if (lane < L4) own = *reinterpret_cast<const float4*>(&x[(size_t)node * DIN + lane * 4]);
        float4 s = make_float4(0.f, 0.f, 0.f, 0.f);
        for (int e = beg + esub; e < end; e += EPA) {
            const int c = col[e];
            const float4 v = *reinterpret_cast<const float4*>(&x[(size_t)c * DIN + rowlane * 4]);
            s.x += v.x; s.y += v.y; s.z += v.z; s.w += v.w;
        }
#pragma unroll
        for (int m = L4; m < 64; m <<= 1) red4(s, m);
        if (lane < L4) {
            float sc = (end > beg) ? 1.0f / (float)(end - beg) : 0.f;
            *reinterpret_cast<float4*>(&msh[kk][lane * 4]) =
                make_float4(s.x * sc, s.y * sc, s.z * sc, s.w * sc);
            *reinterpret_cast<float4*>(&xsh[kk][lane * 4]) = own;
        }
    }
    // same-wave LDS visibility: drain DS queue + compiler fence (no block barrier)
    asm volatile("s_waitcnt lgkmcnt(0)" ::: "memory");
    __builtin_amdgcn_wave_barrier();
    // ---- phase B ----
    const int jq = lane % JQ;
    const int nd = lane / JQ;
    const float4 bv = *reinterpret_cast<const float4*>(&bias[jq * 4]);
    float4 acc[NSL];
#pragma unroll
    for (int sl = 0; sl < NSL; ++sl) acc[sl] = bv;
#pragma unroll 2
    for (int i = 0; i < DIN; i += 4) {
        const float4 w0 = *reinterpret_cast<const float4*>(&Ws[(i + 0) * DOUT + jq * 4]);
        const float4 w1 = *reinterpret_cast<const float4*>(&Ws[(i + 1) * DOUT + jq * 4]);
        const float4 w2 = *reinterpret_cast<const float4*>(&Ws[(i + 2) * DOUT + jq * 4]);
        const float4 w3 = *reinterpret_cast<const float4*>(&Ws[(i + 3) * DOUT + jq * 4]);
        const float4 u0 = *reinterpret_cast<const float4*>(&Wn[(i + 0) * DOUT + jq * 4]);
        const float4 u1 = *reinterpret_cast<const float4*>(&Wn[(i + 1) * DOUT + jq * 4]);
        const float4 u2 = *reinterpret_cast<const float4*>(&Wn[(i + 2) * DOUT + jq * 4]);
        const float4 u3 = *reinterpret_cast<const float4*>(&Wn[(i + 3) * DOUT + jq * 4]);
#pragma unroll
        for (int sl = 0; sl < NSL; ++sl) {
            const int kk = wave * NW + sl * NDP + nd;
            const float4 xv = *reinterpret_cast<const float4*>(&xsh[kk][i]);
            const float4 mv = *reinterpret_cast<const float4*>(&msh[kk][i]);
            fma4(acc[sl], xv.x, w0); fma4(acc[sl], xv.y, w1);
            fma4(acc[sl], xv.z, w2); fma4(acc[sl], xv.w, w3);
            fma4(acc[sl], mv.x, u0); fma4(acc[sl], mv.y, u1);
            fma4(acc[sl], mv.z, u2); fma4(acc[sl], mv.w, u3);
        }
    }
#pragma unroll
    for (int sl = 0; sl < NSL; ++sl) {
        const int kk = wave * NW + sl * NDP + nd;
        float4 o = make_float4(tanhf(acc[sl].x), tanhf(acc[sl].y),
                               tanhf(acc[sl].z), tanhf(acc[sl].w));
        *reinterpret_cast<float4*>(&h[(size_t)(blockBase + kk) * DOUT + jq * 4]) = o;
    }
}

// ===== fused concat+SAGE for up-layers: cat row = [xup[asgn[s]](32f), xlo[s](32f)] =====

template<int DOUT>
__global__ __launch_bounds__(512) void sage_cat(const float* __restrict__ xup,
                       const int* __restrict__ asgn, const float* __restrict__ xlo,
                       const int* __restrict__ rp, const int* __restrict__ col,
                       const float* __restrict__ Ws, const float* __restrict__ Wn,
                       const float* __restrict__ bias, float* __restrict__ h, int n) {
    constexpr int DIN = 64;
    constexpr int NW  = 8;
    constexpr int NPB = 64;
    constexpr int L4  = 16;
    constexpr int EPA = 4;
    constexpr int SD  = DIN + 4;
    constexpr int JQ  = DOUT / 4;
    constexpr int NDP = 64 / JQ;
    constexpr int NSL = NW / NDP;
    __shared__ float xsh[NPB][SD];
    __shared__ float msh[NPB][SD];
    const int wave = threadIdx.x >> 6;
    const int lane = threadIdx.x & 63;
    const int rowlane = lane % L4;
    const int esub = lane / L4;
    const int up = (rowlane < 8);
    const int sub4 = (rowlane & 7) * 4;
    const int blockBase = blockIdx.x * NPB;
#pragma unroll
    for (int k = 0; k < NW; ++k) {
        const int kk = wave * NW + k;
        const int node = blockBase + kk;
        const int beg = rp[node], end = rp[node + 1];
        float4 own = make_float4(0.f, 0.f, 0.f, 0.f);
        if (lane < L4) {
            int cc = up ? asgn[node] : node;
            const float* base = up ? xup : xlo;
            own = *reinterpret_cast<const float4*>(&base[(size_t)cc * 32 + sub4]);
        }
        float4 s = make_float4(0.f, 0.f, 0.f, 0.f);
        for (int e = beg + esub; e < end; e += EPA) {
            const int c = col[e];
            const int cc = up ? asgn[c] : c;
            const float* base = up ? xup : xlo;
            const float4 v = *reinterpret_cast<const float4*>(&base[(size_t)cc * 32 + sub4]);
            s.x += v.x; s.y += v.y; s.z += v.z; s.w += v.w;
        }
#pragma unroll
        for (int m = L4; m < 64; m <<= 1) red4(s, m);
        if (lane < L4) {
            float sc = (end > beg) ? 1.0f / (float)(end - beg) : 0.f;
            *reinterpret_cast<float4*>(&msh[kk][lane * 4]) =
                make_float4(s.x * sc, s.y * sc, s.z * sc, s.w * sc);
            *reinterpret_cast<float4*>(&xsh[kk][lane * 4]) = own;
        }
    }
    asm volatile("s_waitcnt lgkmcnt(0)" ::: "memory");
    __builtin_amdgcn_wave_barrier();
    const int jq = lane % JQ;
    const int nd = lane / JQ;
    const float4 bv = *reinterpret_cast<const float4*>(&bias[jq * 4]);
    float4 acc[NSL];
#pragma unroll
    for (int sl = 0; sl < NSL; ++sl) acc[sl] = bv;
#pragma unroll 2
    for (int i = 0; i < DIN; i += 4) {
        const float4 w0 = *reinterpret_cast<const float4*>(&Ws[(i + 0) * DOUT + jq * 4]);
        const float4 w1 = *reinterpret_cast<const float4*>(&Ws[(i + 1) * DOUT + jq * 4]);
        const float4 w2 = *reinterpret_cast<const float4*>(&Ws[(i + 2) * DOUT + jq * 4]);
        const float4 w3 = *reinterpret_cast<const float4*>(&Ws[(i + 3) * DOUT + jq * 4]);
        const float4 u0 = *reinterpret_cast<const float4*>(&Wn[(i + 0) * DOUT + jq * 4]);
        const float4 u1 = *reinterpret_cast<const float4*>(&Wn[(i + 1) * DOUT + jq * 4]);
        const float4 u2 = *reinterpret_cast<const float4*>(&Wn[(i + 2) * DOUT + jq * 4]);
        const float4 u3 = *reinterpret_cast<const float4*>(&Wn[(i + 3) * DOUT + jq * 4]);
#pragma unroll
        for (int sl = 0; sl < NSL; ++sl) {
            const int kk = wave * NW + sl * NDP + nd;
            const float4 xv = *reinterpret_cast<const float4*>(&xsh[kk][i]);
            const float4 mv = *reinterpret_cast<const float4*>(&msh[kk][i]);
            fma4(acc[sl], xv.x, w0); fma4(acc[sl], xv.y, w1);
            fma4(acc[sl], xv.z, w2); fma4(acc[sl], xv.w, w3);
            fma4(acc[sl], mv.x, u0); fma4(acc[sl], mv.y, u1);
            fma4(acc[sl], mv.z, u2); fma4(acc[sl], mv.w, u3);
        }
    }
#pragma unroll
    for (int sl = 0; sl < NSL; ++sl) {
        const int kk = wave * NW + sl * NDP + nd;
        float4 o = make_float4(tanhf(acc[sl].x), tanhf(acc[sl].y),
                               tanhf(acc[sl].z), tanhf(acc[sl].w));
        *reinterpret_cast<float4*>(&h[(size_t)(blockBase + kk) * DOUT + jq * 4]) = o;
    }
}

// ===== pooling mean via CSR gather =====

template<int F>
__global__ void csr_mean(const float* __restrict__ x, const int* __restrict__ rp,
                         const int* __restrict__ col, float* __restrict__ out, int n) {
    constexpr int G = 32, L4 = F / 4, EP = G / L4;
    int g = threadIdx.x / G, tg = threadIdx.x % G;
    int rowlane = tg % L4, esub = tg / L4;
    int seg = blockIdx.x * (256 / G) + g;
    if (seg >= n) return;
    int beg = rp[seg], end = rp[seg + 1];
    float4 s = make_float4(0.f, 0.f, 0.f, 0.f);
    for (int e = beg + esub; e < end; e += EP) {
        int c = col[e];
        const float4 v = *reinterpret_cast<const float4*>(&x[(size_t)c * F + rowlane * 4]);
        s.x += v.x; s.y += v.y; s.z += v.z; s.w += v.w;
    }
#pragma unroll
    for (int m = L4; m < G; m <<= 1) red4(s, m);
    if (esub == 0) {
        float sc = (end > beg) ? 1.0f / (float)(end - beg) : 0.f;
        *reinterpret_cast<float4*>(&out[(size_t)seg * F + rowlane * 4]) =
            make_float4(s.x * sc, s.y * sc, s.z * sc, s.w * sc);
    }
}

// ===== fused conn-max + MLP =====

__global__ __launch_bounds__(512) void mlp_kernel(const float* __restrict__ h0b,
                           const int* __restrict__ rp, const int* __restrict__ col,
                           const float* __restrict__ xnet,
                           const float* __restrict__ w1, const float* __restrict__ b1,
                           const float* __restrict__ w2, const float* __restrict__ b2,
                           float* __restrict__ out) {
    constexpr int SD = 84;
    __shared__ float w1T[64 * SD];
    __shared__ float w2s[64];
    __shared__ float xin[8][SD];
    for (int idx = threadIdx.x; idx < 80 * 64; idx += 512) {
        int i = idx / 64, j = idx % 64;
        w1T[j * SD + i] = w1[idx];
    }
    if (threadIdx.x < 64) w2s[threadIdx.x] = w2[threadIdx.x];
    __syncthreads();
    int wv = threadIdx.x >> 6;
    int lane = threadIdx.x & 63;
    int rowlane = lane & 15, esub = lane >> 4;
    for (int r = 0; r < 4; ++r) {
        int net = blockIdx.x * 32 + r * 8 + wv;
        int beg = rp[net], end = rp[net + 1];
        float4 m = make_float4(-INFINITY, -INFINITY, -INFINITY, -INFINITY);
        for (int e = beg + esub; e < end; e += 4) {
            int c = col[e];
            const float4 v = *reinterpret_cast<const float4*>(&h0b[(size_t)c * 64 + rowlane * 4]);
            m.x = fmaxf(m.x, v.x); m.y = fmaxf(m.y, v.y);
            m.z = fmaxf(m.z, v.z); m.w = fmaxf(m.w, v.w);
        }
#pragma unroll
        for (int msk = 16; msk < 64; msk <<= 1) {
            m.x = fmaxf(m.x, __shfl_xor(m.x, msk, 64));
            m.y = fmaxf(m.y, __shfl_xor(m.y, msk, 64));
            m.z = fmaxf(m.z, __shfl_xor(m.z, msk, 64));
            m.w = fmaxf(m.w, __shfl_xor(m.w, msk, 64));
        }
        if (beg == end) m = make_float4(0.f, 0.f, 0.f, 0.f);
        if (esub == 0) *reinterpret_cast<float4*>(&xin[wv][rowlane * 4]) = m;
        else if (esub == 1) xin[wv][64 + rowlane] = xnet[(size_t)net * 16 + rowlane];
        float acc = b1[lane];
#pragma unroll
        for (int i = 0; i < 80; i += 4) {
            const float4 w4 = *reinterpret_cast<const float4*>(&w1T[lane * SD + i]);
            const float4 xv = *reinterpret_cast<const float4*>(&xin[wv][i]);
            acc += xv.x * w4.x + xv.y * w4.y + xv.z * w4.z + xv.w * w4.w;
        }
        float p = tanhf(acc) * w2s[lane];
#pragma unroll
        for (int off = 32; off > 0; off >>= 1) p += __shfl_down(p, off, 64);
        if (lane == 0) out[net] = p + b2[0];
    }
}

// ===== host =====

extern "C" void kernel_launch(void* const* d_in, const int* in_sizes, int n_in,
                              void* d_out, int out_size, void* d_ws, size_t ws_size,
                              hipStream_t stream) {
    (void)in_sizes; (void)n_in; (void)out_size; (void)ws_size;
    const float* x0   = (const float*)d_in[0];
    const float* xnet = (const float*)d_in[1];
    const float* Ws0 = (const float*)d_in[2];  const float* Wn0 = (const float*)d_in[3];  const float* b0 = (const float*)d_in[4];
    const float* Ws1 = (const float*)d_in[5];  const float* Wn1 = (const float*)d_in[6];  const float* b1 = (const float*)d_in[7];
    const float* Ws2 = (const float*)d_in[8];  const float* Wn2 = (const float*)d_in[9];  const float* b2 = (const float*)d_in[10];
    const float* Ws3 = (const float*)d_in[11]; const float* Wn3 = (const float*)d_in[12]; const float* b3 = (const float*)d_in[13];
    const float* Ws4 = (const float*)d_in[14]; const float* Wn4 = (const float*)d_in[15]; const float* b4 = (const float*)d_in[16];
    const float* mw1 = (const float*)d_in[17]; const float* mb1 = (const float*)d_in[18];
    const float* mw2 = (const float*)d_in[19]; const float* mb2 = (const float*)d_in[20];
    const int* e0s = (const int*)d_in[21]; const int* e0d = (const int*)d_in[22];
    const int* e1s = (const int*)d_in[23]; const int* e1d = (const int*)d_in[24];
    const int* e2s = (const int*)d_in[25]; const int* e2d = (const int*)d_in[26];
    const int* a01 = (const int*)d_in[27]; const int* a12 = (const int*)d_in[28];
    const int* cs  = (const int*)d_in[29]; const int* cd  = (const int*)d_in[30];

    char* ws = (char*)d_ws;
    const size_t MB = 1u << 20;
    int* rp0    = (int*)(ws + (size_t)(0.00 * MB));
    int* rp1    = (int*)(ws + (size_t)(1.25 * MB));
    int* rp2    = (int*)(ws + (size_t)(1.75 * MB));
    int* rpA01  = (int*)(ws + (size_t)(2.00 * MB));
    int* rpA12  = (int*)(ws + (size_t)(2.50 * MB));
    int* rpC    = (int*)(ws + (size_t)(2.75 * MB));
    int* bcnt   = (int*)(ws + (size_t)(3.75 * MB));
    int* bs     = (int*)(ws + (size_t)(3.75 * MB) + 4096);
    int* cur    = (int*)(ws + (size_t)(3.75 * MB) + 8192);
    int* colAll = (int*)(ws + (size_t)(4.00 * MB));   // 14.8MB -> ends ~18.8
    float* h0   = (float*)(ws + 19 * MB);   // 32MB -> 51
    float* h1   = (float*)(ws + 51 * MB);   // 8MB  -> 59
    float* h2   = (float*)(ws + 59 * MB);   // 2MB  -> 61
    float* x1   = (float*)(ws + 61 * MB);   // 8MB  -> 69
    float* x2   = (float*)(ws + 69 * MB);   // 2MB  -> 71
    float* h1b  = (float*)(ws + 71 * MB);   // 8MB  -> 79
    float* h0b  = (float*)(ws + 79 * MB);   // 64MB -> 143
    int2* bin   = (int2*)(ws + 79 * MB);    // 31MB, dead (after bbuild) before h0b written

    // ---- binned CSR build ----
    hipMemsetAsync(bcnt, 0, NBK_TOT * 4, stream);
    bcount<<<dim3(CBT), 256, 0, stream>>>(e0d, e1d, e2d, a01, a12, cd, bcnt);
    bscan<<<dim3(1), 1024, 0, stream>>>(bcnt, bs, cur);
    bscatter<<<dim3(CBT), 256, 0, stream>>>(e0s, e0d, e1s, e1d, e2s, e2d, a01, a12, cs, cd,
                                            cur, bin);
    bbuild<<<dim3(NBK_TOT), 512, 0, stream>>>(bin, bs, colAll,
                                              rp0, rp1, rp2, rpA01, rpA12, rpC);

    // ---- layer 0: h0 = sage(x0, e0)  [N0,32]
    sage_b<16, 32><<<dim3(N0 / 64), 512, 0, stream>>>(x0, rp0, colAll, Ws0, Wn0, b0, h0, N0);
    // ---- pool 0->1: x1 = seg_mean(h0, assign01)  [N1,32]
    csr_mean<32><<<dim3(N1 / 8), 256, 0, stream>>>(h0, rpA01, colAll, x1, N1);
    // ---- layer 1: h1 = sage(x1, e1)  [N1,32]
    sage_b<32, 32><<<dim3(N1 / 64), 512, 0, stream>>>(x1, rp1, colAll, Ws1, Wn1, b1, h1, N1);
    // ---- pool 1->2: x2 = seg_mean(h1, assign12)  [N2,32]
    csr_mean<32><<<dim3(N2 / 8), 256, 0, stream>>>(h1, rpA12, colAll, x2, N2);
    // ---- layer 2: h2 = sage(x2, e2)  [N2,32]
    sage_b<32, 32><<<dim3(N2 / 64), 512, 0, stream>>>(x2, rp2, colAll, Ws2, Wn2, b2, h2, N2);
    // ---- up 2->1: h1b = sage([h2[a12[.]], h1], e1)  [N1,32] (concat fused)
    sage_cat<32><<<dim3(N1 / 64), 512, 0, stream>>>(h2, a12, h1, rp1, colAll,
                                                    Ws3, Wn3, b3, h1b, N1);
    // ---- up 1->0: h0b = sage([h1b[a01[.]], h0], e0)  [N0,64] (concat fused)
    sage_cat<64><<<dim3(N0 / 64), 512, 0, stream>>>(h1b, a01, h0, rp0, colAll,
                                                    Ws4, Wn4, b4, h0b, N0);
    // ---- fused per-net segment-max + MLP -> out [NNET,1]
    mlp_kernel<<<dim3(NNET / 32), 512, 0, stream>>>(h0b, rpC, colAll, xnet, mw1, mb1, mw2, mb2,
                                                    (float*)d_out);
}

// Round 9
// 687.773 us; speedup vs baseline: 1.7355x; 1.0578x over previous
//
#include <hip/hip_runtime.h>

#define N0 262144
#define N1 65536
#define N2 16384
#define NNET 200000
#define E0 2097152
#define E1 524288
#define E2 131072
#define ECONN 800000

// ===== binned CSR build =====
#define BSH 10
#define NBK_TOT 612
#define CHK 16384
#define CBT 237

__global__ void bcount(const int* __restrict__ e0d, const int* __restrict__ e1d,
                       const int* __restrict__ e2d, const int* __restrict__ a01,
                       const int* __restrict__ a12, const int* __restrict__ cd,
                       int* __restrict__ bcnt) {
    int bb = blockIdx.x; int lb, nE, nbuk, gb; const int* dst;
    if (bb < 128)      { lb=bb;     dst=e0d; nE=E0;    nbuk=256; gb=0; }
    else if (bb < 160) { lb=bb-128; dst=e1d; nE=E1;    nbuk=64;  gb=256; }
    else if (bb < 168) { lb=bb-160; dst=e2d; nE=E2;    nbuk=16;  gb=320; }
    else if (bb < 184) { lb=bb-168; dst=a01; nE=N0;    nbuk=64;  gb=336; }
    else if (bb < 188) { lb=bb-184; dst=a12; nE=N1;    nbuk=16;  gb=400; }
    else               { lb=bb-188; dst=cd;  nE=ECONN; nbuk=196; gb=416; }
    __shared__ int h[256];
    for (int i = threadIdx.x; i < nbuk; i += 256) h[i] = 0;
    __syncthreads();
    int base = lb * CHK;
    for (int k = 0; k < CHK / 256; ++k) {
        int e = base + k * 256 + threadIdx.x;
        if (e < nE) atomicAdd(&h[dst[e] >> BSH], 1);
    }
    __syncthreads();
    for (int i = threadIdx.x; i < nbuk; i += 256)
        if (h[i]) atomicAdd(&bcnt[gb + i], h[i]);
}

__global__ __launch_bounds__(1024) void bscan(const int* __restrict__ bcnt,
                                              int* __restrict__ bs, int* __restrict__ cur) {
    __shared__ int ts[1024];
    int t = threadIdx.x;
    int v = (t < NBK_TOT) ? bcnt[t] : 0;
    ts[t] = v; __syncthreads();
    for (int off = 1; off < 1024; off <<= 1) {
        int u = (t >= off) ? ts[t - off] : 0; __syncthreads();
        ts[t] += u; __syncthreads();
    }
    if (t < NBK_TOT) {
        int ex = ts[t] - v;
        bs[t] = ex; cur[t] = ex;
        if (t == NBK_TOT - 1) bs[NBK_TOT] = ts[t];
    }
}

__global__ void bscatter(const int* e0s, const int* e0d, const int* e1s, const int* e1d,
                         const int* e2s, const int* e2d, const int* a01, const int* a12,
                         const int* cs, const int* cd,
                         int* __restrict__ cur, int2* __restrict__ bin) {
    int bb = blockIdx.x; int lb, nE, nbuk, gb; const int* dst; const int* src;
    if (bb < 128)      { lb=bb;     dst=e0d; src=e0s;     nE=E0;    nbuk=256; gb=0; }
    else if (bb < 160) { lb=bb-128; dst=e1d; src=e1s;     nE=E1;    nbuk=64;  gb=256; }
    else if (bb < 168) { lb=bb-160; dst=e2d; src=e2s;     nE=E2;    nbuk=16;  gb=320; }
    else if (bb < 184) { lb=bb-168; dst=a01; src=nullptr; nE=N0;    nbuk=64;  gb=336; }
    else if (bb < 188) { lb=bb-184; dst=a12; src=nullptr; nE=N1;    nbuk=16;  gb=400; }
    else               { lb=bb-188; dst=cd;  src=cs;      nE=ECONN; nbuk=196; gb=416; }
    __shared__ int h[256];
    __shared__ int curl[256];
    for (int i = threadIdx.x; i < nbuk; i += 256) h[i] = 0;
    __syncthreads();
    int base = lb * CHK;
    for (int k = 0; k < CHK / 256; ++k) {
        int e = base + k * 256 + threadIdx.x;
        if (e < nE) atomicAdd(&h[dst[e] >> BSH], 1);
    }
    __syncthreads();
    for (int i = threadIdx.x; i < nbuk; i += 256)
        if (h[i]) curl[i] = atomicAdd(&cur[gb + i], h[i]);
    __syncthreads();
    for (int k = 0; k < CHK / 256; ++k) {
        int e = base + k * 256 + threadIdx.x;
        if (e < nE) {
            int d = dst[e];
            int pos = atomicAdd(&curl[d >> BSH], 1);
            bin[pos] = make_int2(d, src ? src[e] : e);
        }
    }
}

__global__ __launch_bounds__(512) void bbuild(const int2* __restrict__ bin,
                        const int* __restrict__ bs, int* __restrict__ colAll,
                        int* rp0, int* rp1, int* rp2, int* rpA01, int* rpA12, int* rpC) {
    int g = blockIdx.x; int lb, nSeg, last; int* rp;
    if (g < 256)      { lb=g;     nSeg=N0;   rp=rp0;   last=(g==255); }
    else if (g < 320) { lb=g-256; nSeg=N1;   rp=rp1;   last=(g==319); }
    else if (g < 336) { lb=g-320; nSeg=N2;   rp=rp2;   last=(g==335); }
    else if (g < 400) { lb=g-336; nSeg=N1;   rp=rpA01; last=(g==399); }
    else if (g < 416) { lb=g-400; nSeg=N2;   rp=rpA12; last=(g==415); }
    else              { lb=g-416; nSeg=NNET; rp=rpC;   last=(g==611); }
    const int nodeBase = lb << BSH;
    const int begE = bs[g], endE = bs[g + 1];
    __shared__ int cnt[1024];
    __shared__ int rpl[1024];
    __shared__ int ts[512];
    const int t = threadIdx.x;
    cnt[t] = 0; cnt[t + 512] = 0;
    __syncthreads();
    for (int e = begE + t; e < endE; e += 512)
        atomicAdd(&cnt[bin[e].x - nodeBase], 1);
    __syncthreads();
    int a = cnt[2 * t], b = cnt[2 * t + 1];
    int s = a + b;
    ts[t] = s; __syncthreads();
    for (int off = 1; off < 512; off <<= 1) {
        int u = (t >= off) ? ts[t - off] : 0; __syncthreads();
        ts[t] += u; __syncthreads();
    }
    int pre = ts[t] - s;
    rpl[2 * t] = pre; rpl[2 * t + 1] = pre + a;
    __syncthreads();
    int lim = nSeg - nodeBase; if (lim > 1024) lim = 1024;
    for (int i = t; i < lim; i += 512) {
        int abs0 = begE + rpl[i];
        rp[nodeBase + i] = abs0;
        cnt[i] = abs0;
    }
    if (last && t == 0) rp[nSeg] = endE;
    __syncthreads();
    for (int e = begE + t; e < endE; e += 512) {
        int2 p = bin[e];
        int pos = atomicAdd(&cnt[p.x - nodeBase], 1);
        colAll[pos] = p.y;
    }
}

// ===== colPair: (col, asgn[col]) packed per e0/e1 CSR slot (kills the
// dependent asgn load in sage_cat's inner gather loop) =====
__global__ void colpair_kernel(const int* __restrict__ colAll,
                               const int* __restrict__ a01, const int* __restrict__ a12,
                               int2* __restrict__ colPair) {
    int i = blockIdx.x * blockDim.x + threadIdx.x;   // grid covers exactly E0+E1
    int c = colAll[i];
    int up = (i < E0) ? a01[c] : a12[c];
    colPair[i] = make_int2(c, up);
}

// ===== helpers =====
__device__ __forceinline__ void fma4(float4& a, float s, const float4& b) {
    a.x = fmaf(s, b.x, a.x); a.y = fmaf(s, b.y, a.y);
    a.z = fmaf(s, b.z, a.z); a.w = fmaf(s, b.w, a.w);
}
__device__ __forceinline__ void red4(float4& s, int m) {
    s.x += __shfl_xor(s.x, m, 64);
    s.y += __shfl_xor(s.y, m, 64);
    s.z += __shfl_xor(s.z, m, 64);
    s.w += __shfl_xor(s.w, m, 64);
}

// ===== fused SAGE, barrier-free =====

template<int DIN, int DOUT>
__global__ __launch_bounds__(512) void sage_b(const float* __restrict__ x,
                       const int* __restrict__ rp, const int* __restrict__ col,
                       const float* __restrict__ Ws, const float* __restrict__ Wn,
                       const float* __restrict__ bias, float* __restrict__ h, int n) {
    constexpr int NW  = 8;
    constexpr int NPB = 64;
    constexpr int L4  = DIN / 4;
    constexpr int EPA = 64 / L4;
    constexpr int SD  = DIN + 4;
    constexpr int JQ  = DOUT / 4;
    constexpr int NDP = 64 / JQ;
    constexpr int NSL = NW / NDP;
    __shared__ float xsh[NPB][SD];
    __shared__ float msh[NPB][SD];
    const int wave = threadIdx.x >> 6;
    const int lane = threadIdx.x & 63;
    const int rowlane = lane % L4;
    const int esub = lane / L4;
    const int blockBase = blockIdx.x * NPB;
#pragma unroll
    for (int k = 0; k < NW; ++k) {
        const int kk = wave * NW + k;
        const int node = blockBase + kk;
        const int beg = rp[node], end = rp[node + 1];
        float4 own = make_float4(0.f, 0.f, 0.f, 0.f);
        if (lane < L4) own = *reinterpret_cast<const float4*>(&x[(size_t)node * DIN + lane * 4]);
        float4 s = make_float4(0.f, 0.f, 0.f, 0.f);
#pragma unroll 2
        for (int e = beg + esub; e < end; e += EPA) {
            const int c = col[e];
            const float4 v = *reinterpret_cast<const float4*>(&x[(size_t)c * DIN + rowlane * 4]);
            s.x += v.x; s.y += v.y; s.z += v.z; s.w += v.w;
        }
#pragma unroll
        for (int m = L4; m < 64; m <<= 1) red4(s, m);
        if (lane < L4) {
            float sc = (end > beg) ? 1.0f / (float)(end - beg) : 0.f;
            *reinterpret_cast<float4*>(&msh[kk][lane * 4]) =
                make_float4(s.x * sc, s.y * sc, s.z * sc, s.w * sc);
            *reinterpret_cast<float4*>(&xsh[kk][lane * 4]) = own;
        }
    }
    asm volatile("s_waitcnt lgkmcnt(0)" ::: "memory");
    __builtin_amdgcn_wave_barrier();
    const int jq = lane % JQ;
    const int nd = lane / JQ;
    const float4 bv = *reinterpret_cast<const float4*>(&bias[jq * 4]);
    float4 acc[NSL];
#pragma unroll
    for (int sl = 0; sl < NSL; ++sl) acc[sl] = bv;
#pragma unroll 2
    for (int i = 0; i < DIN; i += 4) {
        const float4 w0 = *reinterpret_cast<const float4*>(&Ws[(i + 0) * DOUT + jq * 4]);
        const float4 w1 = *reinterpret_cast<const float4*>(&Ws[(i + 1) * DOUT + jq * 4]);
        const float4 w2 = *reinterpret_cast<const float4*>(&Ws[(i + 2) * DOUT + jq * 4]);
        const float4 w3 = *reinterpret_cast<const float4*>(&Ws[(i + 3) * DOUT + jq * 4]);
        const float4 u0 = *reinterpret_cast<const float4*>(&Wn[(i + 0) * DOUT + jq * 4]);
        const float4 u1 = *reinterpret_cast<const float4*>(&Wn[(i + 1) * DOUT + jq * 4]);
        const float4 u2 = *reinterpret_cast<const float4*>(&Wn[(i + 2) * DOUT + jq * 4]);
        const float4 u3 = *reinterpret_cast<const float4*>(&Wn[(i + 3) * DOUT + jq * 4]);
#pragma unroll
        for (int sl = 0; sl < NSL; ++sl) {
            const int kk = wave * NW + sl * NDP + nd;
            const float4 xv = *reinterpret_cast<const float4*>(&xsh[kk][i]);
            const float4 mv = *reinterpret_cast<const float4*>(&msh[kk][i]);
            fma4(acc[sl], xv.x, w0); fma4(acc[sl], xv.y, w1);
            fma4(acc[sl], xv.z, w2); fma4(acc[sl], xv.w, w3);
            fma4(acc[sl], mv.x, u0); fma4(acc[sl], mv.y, u1);
            fma4(acc[sl], mv.z, u2); fma4(acc[sl], mv.w, u3);
        }
    }
#pragma unroll
    for (int sl = 0; sl < NSL; ++sl) {
        const int kk = wave * NW + sl * NDP + nd;
        float4 o = make_float4(tanhf(acc[sl].x), tanhf(acc[sl].y),
                               tanhf(acc[sl].z), tanhf(acc[sl].w));
        *reinterpret_cast<float4*>(&h[(size_t)(blockBase + kk) * DOUT + jq * 4]) = o;
    }
}

// ===== fused concat+SAGE for up-layers, colPair edition =====

template<int DOUT>
__global__ __launch_bounds__(512) void sage_cat(const float* __restrict__ xup,
                       const int* __restrict__ asgn, const float* __restrict__ xlo,
                       const int* __restrict__ rp, const int2* __restrict__ colPair,
                       const float* __restrict__ Ws, const float* __restrict__ Wn,
                       const float* __restrict__ bias, float* __restrict__ h, int n) {
    constexpr int DIN = 64;
    constexpr int NW  = 8;
    constexpr int NPB = 64;
    constexpr int L4  = 16;
    constexpr int EPA = 4;
    constexpr int SD  = DIN + 4;
    constexpr int JQ  = DOUT / 4;
    constexpr int NDP = 64 / JQ;
    constexpr int NSL = NW / NDP;
    __shared__ float xsh[NPB][SD];
    __shared__ float msh[NPB][SD];
    const int wave = threadIdx.x >> 6;
    const int lane = threadIdx.x & 63;
    const int rowlane = lane % L4;
    const int esub = lane / L4;
    const int up = (rowlane < 8);
    const int sub4 = (rowlane & 7) * 4;
    const int blockBase = blockIdx.x * NPB;
#pragma unroll
    for (int k = 0; k < NW; ++k) {
        const int kk = wave * NW + k;
        const int node = blockBase + kk;
        const int beg = rp[node], end = rp[node + 1];
        const float* base = up ? xup : xlo;
        float4 own = make_float4(0.f, 0.f, 0.f, 0.f);
        if (lane < L4) {
            int cc = up ? asgn[node] : node;
            own = *reinterpret_cast<const float4*>(&base[(size_t)cc * 32 + sub4]);
        }
        float4 s = make_float4(0.f, 0.f, 0.f, 0.f);
#pragma unroll 2
        for (int e = beg + esub; e < end; e += EPA) {
            const int2 p = colPair[e];
            const int cc = up ? p.y : p.x;
            const float4 v = *reinterpret_cast<const float4*>(&base[(size_t)cc * 32 + sub4]);
            s.x += v.x; s.y += v.y; s.z += v.z; s.w += v.w;
        }
#pragma unroll
        for (int m = L4; m < 64; m <<= 1) red4(s, m);
        if (lane < L4) {
            float sc = (end > beg) ? 1.0f / (float)(end - beg) : 0.f;
            *reinterpret_cast<float4*>(&msh[kk][lane * 4]) =
                make_float4(s.x * sc, s.y * sc, s.z * sc, s.w * sc);
            *reinterpret_cast<float4*>(&xsh[kk][lane * 4]) = own;
        }
    }
    asm volatile("s_waitcnt lgkmcnt(0)" ::: "memory");
    __builtin_amdgcn_wave_barrier();
    const int jq = lane % JQ;
    const int nd = lane / JQ;
    const float4 bv = *reinterpret_cast<const float4*>(&bias[jq * 4]);
    float4 acc[NSL];
#pragma unroll
    for (int sl = 0; sl < NSL; ++sl) acc[sl] = bv;
#pragma unroll 2
    for (int i = 0; i < DIN; i += 4) {
        const float4 w0 = *reinterpret_cast<const float4*>(&Ws[(i + 0) * DOUT + jq * 4]);
        const float4 w1 = *reinterpret_cast<const float4*>(&Ws[(i + 1) * DOUT + jq * 4]);
        const float4 w2 = *reinterpret_cast<const float4*>(&Ws[(i + 2) * DOUT + jq * 4]);
        const float4 w3 = *reinterpret_cast<const float4*>(&Ws[(i + 3) * DOUT + jq * 4]);
        const float4 u0 = *reinterpret_cast<const float4*>(&Wn[(i + 0) * DOUT + jq * 4]);
        const float4 u1 = *reinterpret_cast<const float4*>(&Wn[(i + 1) * DOUT + jq * 4]);
        const float4 u2 = *reinterpret_cast<const float4*>(&Wn[(i + 2) * DOUT + jq * 4]);
        const float4 u3 = *reinterpret_cast<const float4*>(&Wn[(i + 3) * DOUT + jq * 4]);
#pragma unroll
        for (int sl = 0; sl < NSL; ++sl) {
            const int kk = wave * NW + sl * NDP + nd;
            const float4 xv = *reinterpret_cast<const float4*>(&xsh[kk][i]);
            const float4 mv = *reinterpret_cast<const float4*>(&msh[kk][i]);
            fma4(acc[sl], xv.x, w0); fma4(acc[sl], xv.y, w1);
            fma4(acc[sl], xv.z, w2); fma4(acc[sl], xv.w, w3);
            fma4(acc[sl], mv.x, u0); fma4(acc[sl], mv.y, u1);
            fma4(acc[sl], mv.z, u2); fma4(acc[sl], mv.w, u3);
        }
    }
#pragma unroll
    for (int sl = 0; sl < NSL; ++sl) {
        const int kk = wave * NW + sl * NDP + nd;
        float4 o = make_float4(tanhf(acc[sl].x), tanhf(acc[sl].y),
                               tanhf(acc[sl].z), tanhf(acc[sl].w));
        *reinterpret_cast<float4*>(&h[(size_t)(blockBase + kk) * DOUT + jq * 4]) = o;
    }
}

// ===== pooling mean via CSR gather =====

template<int F>
__global__ void csr_mean(const float* __restrict__ x, const int* __restrict__ rp,
                         const int* __restrict__ col, float* __restrict__ out, int n) {
    constexpr int G = 32, L4 = F / 4, EP = G / L4;
    int g = threadIdx.x / G, tg = threadIdx.x % G;
    int rowlane = tg % L4, esub = tg / L4;
    int seg = blockIdx.x * (256 / G) + g;
    if (seg >= n) return;
    int beg = rp[seg], end = rp[seg + 1];
    float4 s = make_float4(0.f, 0.f, 0.f, 0.f);
#pragma unroll 2
    for (int e = beg + esub; e < end; e += EP) {
        int c = col[e];
        const float4 v = *reinterpret_cast<const float4*>(&x[(size_t)c * F + rowlane * 4]);
        s.x += v.x; s.y += v.y; s.z += v.z; s.w += v.w;
    }
#pragma unroll
    for (int m = L4; m < G; m <<= 1) red4(s, m);
    if (esub == 0) {
        float sc = (end > beg) ? 1.0f / (float)(end - beg) : 0.f;
        *reinterpret_cast<float4*>(&out[(size_t)seg * F + rowlane * 4]) =
            make_float4(s.x * sc, s.y * sc, s.z * sc, s.w * sc);
    }
}

// ===== fused conn-max + MLP =====

__global__ __launch_bounds__(512) void mlp_kernel(const float* __restrict__ h0b,
                           const int* __restrict__ rp, const int* __restrict__ col,
                           const float* __restrict__ xnet,
                           const float* __restrict__ w1, const float* __restrict__ b1,
                           const float* __restrict__ w2, const float* __restrict__ b2,
                           float* __restrict__ out) {
    constexpr int SD = 84;
    __shared__ float w1T[64 * SD];
    __shared__ float w2s[64];
    __shared__ float xin[8][SD];
    for (int idx = threadIdx.x; idx < 80 * 64; idx += 512) {
        int i = idx / 64, j = idx % 64;
        w1T[j * SD + i] = w1[idx];
    }
    if (threadIdx.x < 64) w2s[threadIdx.x] = w2[threadIdx.x];
    __syncthreads();
    int wv = threadIdx.x >> 6;
    int lane = threadIdx.x & 63;
    int rowlane = lane & 15, esub = lane >> 4;
    for (int r = 0; r < 4; ++r) {
        int net = blockIdx.x * 32 + r * 8 + wv;
        int beg = rp[net], end = rp[net + 1];
        float4 m = make_float4(-INFINITY, -INFINITY, -INFINITY, -INFINITY);
#pragma unroll 2
        for (int e = beg + esub; e < end; e += 4) {
            int c = col[e];
            const float4 v = *reinterpret_cast<const float4*>(&h0b[(size_t)c * 64 + rowlane * 4]);
            m.x = fmaxf(m.x, v.x); m.y = fmaxf(m.y, v.y);
            m.z = fmaxf(m.z, v.z); m.w = fmaxf(m.w, v.w);
        }
#pragma unroll
        for (int msk = 16; msk < 64; msk <<= 1) {
            m.x = fmaxf(m.x, __shfl_xor(m.x, msk, 64));
            m.y = fmaxf(m.y, __shfl_xor(m.y, msk, 64));
            m.z = fmaxf(m.z, __shfl_xor(m.z, msk, 64));
            m.w = fmaxf(m.w, __shfl_xor(m.w, msk, 64));
        }
        if (beg == end) m = make_float4(0.f, 0.f, 0.f, 0.f);
        if (esub == 0) *reinterpret_cast<float4*>(&xin[wv][rowlane * 4]) = m;
        else if (esub == 1) xin[wv][64 + rowlane] = xnet[(size_t)net * 16 + rowlane];
        float acc = b1[lane];
#pragma unroll
        for (int i = 0; i < 80; i += 4) {
            const float4 w4 = *reinterpret_cast<const float4*>(&w1T[lane * SD + i]);
            const float4 xv = *reinterpret_cast<const float4*>(&xin[wv][i]);
            acc += xv.x * w4.x + xv.y * w4.y + xv.z * w4.z + xv.w * w4.w;
        }
        float p = tanhf(acc) * w2s[lane];
#pragma unroll
        for (int off = 32; off > 0; off >>= 1) p += __shfl_down(p, off, 64);
        if (lane == 0) out[net] = p + b2[0];
    }
}

// ===== host =====

extern "C" void kernel_launch(void* const* d_in, const int* in_sizes, int n_in,
                              void* d_out, int out_size, void* d_ws, size_t ws_size,
                              hipStream_t stream) {
    (void)in_sizes; (void)n_in; (void)out_size; (void)ws_size;
    const float* x0   = (const float*)d_in[0];
    const float* xnet = (const float*)d_in[1];
    const float* Ws0 = (const float*)d_in[2];  const float* Wn0 = (const float*)d_in[3];  const float* b0 = (const float*)d_in[4];
    const float* Ws1 = (const float*)d_in[5];  const float* Wn1 = (const float*)d_in[6];  const float* b1 = (const float*)d_in[7];
    const float* Ws2 = (const float*)d_in[8];  const float* Wn2 = (const float*)d_in[9];  const float* b2 = (const float*)d_in[10];
    const float* Ws3 = (const float*)d_in[11]; const float* Wn3 = (const float*)d_in[12]; const float* b3 = (const float*)d_in[13];
    const float* Ws4 = (const float*)d_in[14]; const float* Wn4 = (const float*)d_in[15]; const float* b4 = (const float*)d_in[16];
    const float* mw1 = (const float*)d_in[17]; const float* mb1 = (const float*)d_in[18];
    const float* mw2 = (const float*)d_in[19]; const float* mb2 = (const float*)d_in[20];
    const int* e0s = (const int*)d_in[21]; const int* e0d = (const int*)d_in[22];
    const int* e1s = (const int*)d_in[23]; const int* e1d = (const int*)d_in[24];
    const int* e2s = (const int*)d_in[25]; const int* e2d = (const int*)d_in[26];
    const int* a01 = (const int*)d_in[27]; const int* a12 = (const int*)d_in[28];
    const int* cs  = (const int*)d_in[29]; const int* cd  = (const int*)d_in[30];

    char* ws = (char*)d_ws;
    const size_t MB = 1u << 20;
    int* rp0    = (int*)(ws + (size_t)(0.00 * MB));
    int* rp1    = (int*)(ws + (size_t)(1.25 * MB));
    int* rp2    = (int*)(ws + (size_t)(1.75 * MB));
    int* rpA01  = (int*)(ws + (size_t)(2.00 * MB));
    int* rpA12  = (int*)(ws + (size_t)(2.50 * MB));
    int* rpC    = (int*)(ws + (size_t)(2.75 * MB));
    int* bcnt   = (int*)(ws + (size_t)(3.75 * MB));
    int* bs     = (int*)(ws + (size_t)(3.75 * MB) + 4096);
    int* cur    = (int*)(ws + (size_t)(3.75 * MB) + 8192);
    int* colAll = (int*)(ws + (size_t)(4.00 * MB));     // 14.8MB -> ends ~18.8
    int2* colPair = (int2*)(ws + 19 * MB);              // (E0+E1)*8B = 21MB -> 40
    float* h0   = (float*)(ws + 41 * MB);   // 32MB -> 73
    float* h1   = (float*)(ws + 73 * MB);   // 8MB  -> 81
    float* h2   = (float*)(ws + 81 * MB);   // 2MB  -> 83
    float* x1   = (float*)(ws + 83 * MB);   // 8MB  -> 91
    float* x2   = (float*)(ws + 91 * MB);   // 2MB  -> 93
    float* h1b  = (float*)(ws + 93 * MB);   // 8MB  -> 101
    float* h0b  = (float*)(ws + 101 * MB);  // 64MB -> 165
    int2* bin   = (int2*)(ws + 101 * MB);   // 31MB, dead (after bbuild) before h0b written

    // ---- binned CSR build ----
    hipMemsetAsync(bcnt, 0, NBK_TOT * 4, stream);
    bcount<<<dim3(CBT), 256, 0, stream>>>(e0d, e1d, e2d, a01, a12, cd, bcnt);
    bscan<<<dim3(1), 1024, 0, stream>>>(bcnt, bs, cur);
    bscatter<<<dim3(CBT), 256, 0, stream>>>(e0s, e0d, e1s, e1d, e2s, e2d, a01, a12, cs, cd,
                                            cur, bin);
    bbuild<<<dim3(NBK_TOT), 512, 0, stream>>>(bin, bs, colAll,
                                              rp0, rp1, rp2, rpA01, rpA12, rpC);
    // colPair for e0+e1 regions ([0, E0+E1) of colAll)
    colpair_kernel<<<dim3((E0 + E1) / 256), 256, 0, stream>>>(colAll, a01, a12, colPair);

    // ---- layer 0: h0 = sage(x0, e0)  [N0,32]
    sage_b<16, 32><<<dim3(N0 / 64), 512, 0, stream>>>(x0, rp0, colAll, Ws0, Wn0, b0, h0, N0);
    // ---- pool 0->1: x1 = seg_mean(h0, assign01)  [N1,32]
    csr_mean<32><<<dim3(N1 / 8), 256, 0, stream>>>(h0, rpA01, colAll, x1, N1);
    // ---- layer 1: h1 = sage(x1, e1)  [N1,32]
    sage_b<32, 32><<<dim3(N1 / 64), 512, 0, stream>>>(x1, rp1, colAll, Ws1, Wn1, b1, h1, N1);
    // ---- pool 1->2: x2 = seg_mean(h1, assign12)  [N2,32]
    csr_mean<32><<<dim3(N2 / 8), 256, 0, stream>>>(h1, rpA12, colAll, x2, N2);
    // ---- layer 2: h2 = sage(x2, e2)  [N2,32]
    sage_b<32, 32><<<dim3(N2 / 64), 512, 0, stream>>>(x2, rp2, colAll, Ws2, Wn2, b2, h2, N2);
    // ---- up 2->1: h1b = sage([h2[a12[.]], h1], e1)  [N1,32] (concat fused, colPair)
    sage_cat<32><<<dim3(N1 / 64), 512, 0, stream>>>(h2, a12, h1, rp1, colPair,
                                                    Ws3, Wn3, b3, h1b, N1);
    // ---- up 1->0: h0b = sage([h1b[a01[.]], h0], e0)  [N0,64] (concat fused, colPair)
    sage_cat<64><<<dim3(N0 / 64), 512, 0, stream>>>(h1b, a01, h0, rp0, colPair,
                                                    Ws4, Wn4, b4, h0b, N0);
    // ---- fused per-net segment-max + MLP -> out [NNET,1]
    mlp_kernel<<<dim3(NNET / 32), 512, 0, stream>>>(h0b, rpC, colAll, xnet, mw1, mb1, mw2, mb2,
                                                    (float*)d_out);
}